// Round 1
// baseline (9010.540 us; speedup 1.0000x reference)
//
#include <hip/hip_runtime.h>

// ---------------------------------------------------------------------------
// Seq2Seq LSTM + attention, persistent kernel for MI355X (gfx950)
// B=256, T=512, I=64, H=512, HORIZON=30, NQ=3
// R8: L2-cached communication. Stores stay coherent write-through (sc0|sc1,
// drained at barrier vmcnt(0)); loads are now PLAIN CACHED, made safe by an
// agent-acquire fence (buffer_inv) inside every group barrier. h/x staging is
// served from per-XCD L2 after one L3 fetch (was: every load bypassed L2 to
// L3). Decoder rebalance: P1 = tiles 0..39 + out-tile (1 GEMM/block); dWhh1
// tiles 40..71 moved to P3's idle half (r>=32).
// Carried from R7: conflict-free 3-sync K-split reduction, flag-vote group
// barrier, P2 LDS reads hoisted to registers, ring-4 K-loop, weights in
// registers for encoder.
// ---------------------------------------------------------------------------

typedef _Float16 half_t;
typedef __attribute__((ext_vector_type(8)))  _Float16 f16x8;
typedef __attribute__((ext_vector_type(16))) float    f32x16;

#define MFMA(a,b,c) __builtin_amdgcn_mfma_f32_32x32x16_f16((a),(b),(c),0,0,0)
#define CBAR()      asm volatile("" ::: "memory")

template<int N> __device__ __forceinline__ void waitvm() {
  asm volatile("s_waitcnt vmcnt(%0)" :: "n"(N) : "memory");
}

__device__ __forceinline__ float fsig(float x)  { return 1.0f / (1.0f + __expf(-x)); }
__device__ __forceinline__ float ftanh(float x) { return 1.0f - 2.0f / (1.0f + __expf(2.0f * x)); }

// ---------------- coherent scalar ops ----------------
// Stores: agent-scope relaxed (sc0|sc1 write-through, visible at L3 once
// vmcnt drains). Loads: PLAIN CACHED (R8) — freshness guaranteed by the
// buffer_inv acquire fence in gbarf/gbar_acq.
union FU { float f; unsigned u; };
union HU { _Float16 h; unsigned short u; };
__device__ __forceinline__ float ldfa(const float* p) { return *p; }
__device__ __forceinline__ void stfa(float* p, float v) {
  FU c; c.f = v;
  __hip_atomic_store((unsigned*)p, c.u, __ATOMIC_RELAXED, __HIP_MEMORY_SCOPE_AGENT);
}
__device__ __forceinline__ void stha(half_t* p, float v) {
  HU c; c.h = (half_t)v;
  __hip_atomic_store((unsigned short*)p, c.u, __ATOMIC_RELAXED, __HIP_MEMORY_SCOPE_AGENT);
}
__device__ __forceinline__ void st64(float* p, float a, float b) {
  FU x, y; x.f = a; y.f = b;
  unsigned long long v = (unsigned long long)x.u | ((unsigned long long)y.u << 32);
  __hip_atomic_store((unsigned long long*)p, v, __ATOMIC_RELAXED, __HIP_MEMORY_SCOPE_AGENT);
}
__device__ __forceinline__ void ld64(const float* p, float& a, float& b) {
  float2 v = *(const float2*)p; a = v.x; b = v.y;
}

// ---------------- workspace layout (bytes, inside g_ws) ----------------
static constexpr size_t O_X16 = 0;                             // (T,B,128) f16 x zero-padded
static constexpr size_t O_WL0 = O_X16 + (size_t)512*256*128*2; // 32t x 5c packed  (2048x640)
static constexpr size_t O_WL1 = O_WL0 + (size_t)2048*640*2;    // 32t x 8c packed  (2048x1024)
static constexpr size_t O_WP1 = O_WL1 + (size_t)2048*1024*2;   // 73t x 4c packed  (4672x512)
static constexpr size_t O_WD0 = O_WP1 + (size_t)4672*512*2;    // 32t x 4c packed
static constexpr size_t O_WD1 = O_WD0 + (size_t)2048*512*2;    // 32t x 4c packed
static constexpr size_t O_BL0 = O_WD1 + (size_t)2048*512*2;    // 2048 f32 biases (gate-permuted)
static constexpr size_t O_BL1 = O_BL0 + 8192;
static constexpr size_t O_BD0 = O_BL1 + 8192;
static constexpr size_t O_BD1 = O_BD0 + 8192;
static constexpr size_t O_W0C = O_BD1 + 8192;                  // 2048 f32 dec_Wih0[:,0] permuted
static constexpr size_t O_H0B = O_W0C + 8192;                  // 2 x (256,512) f16 L0 h ping-pong
static constexpr size_t O_H1B = O_H0B + (size_t)2*256*512*2;   // 2 x (256,512) f16 L1 h ping-pong
static constexpr size_t O_HD1 = O_H1B + (size_t)2*256*512*2;   // (256,512) f16 decoder h1
static constexpr size_t O_H0D = O_HD1 + (size_t)256*512*2;     // (256,512) f16 decoder h0
static constexpr size_t O_CTX = O_H0D + (size_t)256*512*2;     // (256,512) f16 context
static constexpr size_t O_C0  = O_CTX + (size_t)256*512*2;     // (256,512) f32 (unused scratch)
static constexpr size_t O_C1  = O_C0  + (size_t)256*512*4;     // (256,512) f32
static constexpr size_t O_INP = O_C1  + (size_t)256*512*4;     // 256 f32
static constexpr size_t O_GAT = O_INP + 1024;                  // (256,4672) f32 gate partials
static constexpr size_t O_EO  = O_GAT + (size_t)256*4672*4;    // (B*T,H) f16 encoder outputs
static constexpr size_t O_EP  = O_EO  + (size_t)256*512*512*2; // (B*T,512) f16 enc_proj
static constexpr size_t WS_NEED = O_EP + (size_t)256*512*512*2;

__device__ __align__(4096) unsigned char g_ws[WS_NEED];
__device__ int g_bar[2048];    // acq/rel barrier lines (phase edges)
__device__ int g_flags[1024];  // 4 groups x 64 block flags

#define WSH(o) ((half_t*)(g_ws + (o)))
#define WSCH(o) ((const half_t*)(g_ws + (o)))
#define WSF(o) ((float*)(g_ws + (o)))
#define WSCF(o) ((const float*)(g_ws + (o)))
#define BLINE(i) (g_bar + ((size_t)(i) << 5))

__device__ __forceinline__ int gperm(int n) { return (n & 3) * 512 + (n >> 2); }

// ------- flag-vote group barrier: zero-contention arrive, ballot poll -------
// Block (g,r) stores flags[g*64+r]=step; wave 0 polls all 64 flags until all
// >= step, then issues an agent-acquire fence (buffer_inv sc1: invalidate
// clean L1/L2 lines) so the plain cached loads of the next phase observe the
// write-through stores of the previous phase. Data coherence = sc0|sc1 stores
// (drained at the entry syncthreads' vmcnt(0)) + per-barrier invalidate.
__device__ __forceinline__ void gbarf(int g, int r, int step) {
  __syncthreads();   // drains vmcnt(0): all coherent stores are L3-visible
  if (threadIdx.x < 64) {
    if (threadIdx.x == 0)
      __hip_atomic_store(&g_flags[(g << 6) + r], step,
                         __ATOMIC_RELAXED, __HIP_MEMORY_SCOPE_AGENT);
    const int* fp = &g_flags[(g << 6) + threadIdx.x];
    for (;;) {
      int v = __hip_atomic_load(fp, __ATOMIC_RELAXED, __HIP_MEMORY_SCOPE_AGENT);
      if (__all(v >= step)) break;
      __builtin_amdgcn_s_sleep(1);
    }
    __builtin_amdgcn_fence(__ATOMIC_ACQUIRE, "agent");  // buffer_inv: L1+L2
  }
  __syncthreads();
}

// Heavy barrier: full release (L2 writeback) / acquire (L2 inv) — phase edges.
__device__ __forceinline__ void gbar_acq(int g, int sub) {
  __syncthreads();
  if (threadIdx.x == 0) {
    int* cnt = BLINE(g * 2 + sub);
    int* mst = BLINE(8 + g);
    int* gs  = BLINE(12 + g * 2 + sub);
    int old = __hip_atomic_load(gs, __ATOMIC_RELAXED, __HIP_MEMORY_SCOPE_AGENT);
    int a = __hip_atomic_fetch_add(cnt, 1, __ATOMIC_ACQ_REL, __HIP_MEMORY_SCOPE_AGENT);
    if (a == 31) {
      __hip_atomic_store(cnt, 0, __ATOMIC_RELAXED, __HIP_MEMORY_SCOPE_AGENT);
      int m = __hip_atomic_fetch_add(mst, 1, __ATOMIC_ACQ_REL, __HIP_MEMORY_SCOPE_AGENT);
      if (m == 1) {
        __hip_atomic_store(mst, 0, __ATOMIC_RELAXED, __HIP_MEMORY_SCOPE_AGENT);
        __hip_atomic_fetch_add(BLINE(12 + g * 2), 1, __ATOMIC_RELEASE, __HIP_MEMORY_SCOPE_AGENT);
        __hip_atomic_fetch_add(BLINE(12 + g * 2 + 1), 1, __ATOMIC_RELEASE, __HIP_MEMORY_SCOPE_AGENT);
      }
    }
    while (__hip_atomic_load(gs, __ATOMIC_RELAXED, __HIP_MEMORY_SCOPE_AGENT) == old)
      __builtin_amdgcn_s_sleep(2);
    (void)__hip_atomic_load(gs, __ATOMIC_ACQUIRE, __HIP_MEMORY_SCOPE_AGENT);
  }
  __syncthreads();
}

// ---------------- GEMM cores: 64x64 tile, K-split over 8 waves (chunk=128) ---
struct Seg { const half_t* p; int stride; int row0; };

template<int AXA, int AXB>
__device__ __forceinline__ void stageA(Seg sa, Seg sb, int cSplit, int c,
                                       int lane, int wid, char* dst) {
  bool isA = c < cSplit;
  Seg s = isA ? sa : sb;
  int kb = (isA ? c : (c - cSplit)) * 128;
  const half_t* g = s.p + (size_t)(s.row0 + (lane & 31)) * s.stride
                        + kb + (wid << 4) + ((lane >> 5) << 3);
  if (isA) {
    __builtin_amdgcn_global_load_lds(
        (const __attribute__((address_space(1))) unsigned int*)g,
        (__attribute__((address_space(3))) unsigned int*)dst, 16, 0, AXA);
    __builtin_amdgcn_global_load_lds(
        (const __attribute__((address_space(1))) unsigned int*)(g + (size_t)32 * s.stride),
        (__attribute__((address_space(3))) unsigned int*)(dst + 1024), 16, 0, AXA);
  } else {
    __builtin_amdgcn_global_load_lds(
        (const __attribute__((address_space(1))) unsigned int*)g,
        (__attribute__((address_space(3))) unsigned int*)dst, 16, 0, AXB);
    __builtin_amdgcn_global_load_lds(
        (const __attribute__((address_space(1))) unsigned int*)(g + (size_t)32 * s.stride),
        (__attribute__((address_space(3))) unsigned int*)(dst + 1024), 16, 0, AXB);
  }
}

// ---- encoder K-body: B in registers, ring-4 staged A ----
template<int C, int NC, int CSPLIT, int AXA, int AXB>
__device__ __forceinline__ void kreg(Seg sa, Seg sb,
                                     const f16x8 (&B0)[8], const f16x8 (&B1)[8],
                                     int lane, int wid, char* asg, f32x16 acc[2][2]) {
  if constexpr (C < NC) {
    constexpr int rem = NC - 1 - C;
    waitvm<2 * (rem < 3 ? rem : 3)>();
    char* ab = asg + (size_t)(((C & 3) * 8 + wid)) * 2048 + lane * 16;
    f16x8 a0 = *(const f16x8*)ab;
    f16x8 a1 = *(const f16x8*)(ab + 1024);
    acc[0][0] = MFMA(a0, B0[C], acc[0][0]);
    acc[0][1] = MFMA(a0, B1[C], acc[0][1]);
    acc[1][0] = MFMA(a1, B0[C], acc[1][0]);
    acc[1][1] = MFMA(a1, B1[C], acc[1][1]);
    if constexpr (C + 4 < NC)
      stageA<AXA, AXB>(sa, sb, CSPLIT, C + 4, lane, wid,
                       asg + (size_t)((((C + 4) & 3) * 8 + wid)) * 2048);
    CBAR();
    kreg<C + 1, NC, CSPLIT, AXA, AXB>(sa, sb, B0, B1, lane, wid, asg, acc);
  }
}

template<int NC, int CSPLIT, int AXA, int AXB>
__device__ __forceinline__ void gemm_regB(Seg sa, Seg sb,
                                          const f16x8 (&B0)[8], const f16x8 (&B1)[8],
                                          int lane, int wid, char* asg, f32x16 acc[2][2]) {
  #pragma unroll
  for (int c = 0; c < (NC < 4 ? NC : 4); c++) {
    stageA<AXA, AXB>(sa, sb, CSPLIT, c, lane, wid, asg + (size_t)((c & 3) * 8 + wid) * 2048);
    CBAR();
  }
  kreg<0, NC, CSPLIT, AXA, AXB>(sa, sb, B0, B1, lane, wid, asg, acc);
}

// ---- streamed-B K-body (NC<=4): all chunks issued upfront ----
template<int C, int NC>
__device__ __forceinline__ void kks(int lane, int wid, char* asg, f32x16 acc[2][2],
                                    f16x8 (&b0)[4], f16x8 (&b1)[4]) {
  if constexpr (C < NC) {
    waitvm<4 * (NC - 1 - C)>();
    char* ab = asg + (size_t)(C * 8 + wid) * 2048 + lane * 16;
    f16x8 a0 = *(const f16x8*)ab;
    f16x8 a1 = *(const f16x8*)(ab + 1024);
    acc[0][0] = MFMA(a0, b0[C], acc[0][0]);
    acc[0][1] = MFMA(a0, b1[C], acc[0][1]);
    acc[1][0] = MFMA(a1, b0[C], acc[1][0]);
    acc[1][1] = MFMA(a1, b1[C], acc[1][1]);
    CBAR();
    kks<C + 1, NC>(lane, wid, asg, acc, b0, b1);
  }
}

template<int NC, int AXA, int AXB>
__device__ __forceinline__ void gemm_ks(Seg sa, Seg sb, int cSplit, const half_t* Wt,
                                        int lane, int wid, char* asg, f32x16 acc[2][2]) {
  const half_t* wb = Wt + (wid << 1) * 512 + lane * 8;
  f16x8 b0[4], b1[4];
  #pragma unroll
  for (int c = 0; c < NC; c++) {
    stageA<AXA, AXB>(sa, sb, cSplit, c, lane, wid, asg + (size_t)(c * 8 + wid) * 2048);
    CBAR();
    b0[c] = *(const f16x8*)(wb + (size_t)c * 8192);
    b1[c] = *(const f16x8*)(wb + (size_t)c * 8192 + 512);
    CBAR();
  }
  kks<0, NC>(lane, wid, asg, acc, b0, b1);
}

// ---------------- K-split reduction: 3 syncs, conflict-free ------------------
__device__ __forceinline__ void acc_wr(float* dst, int lane, f32x16 acc[2][2]) {
  #pragma unroll
  for (int t = 0; t < 4; t++) {
    f32x16 a = acc[t >> 1][t & 1];
    #pragma unroll
    for (int r4 = 0; r4 < 4; r4++)
      *(float4*)(dst + ((t * 4 + r4) * 64 + lane) * 4) =
          make_float4(a[r4*4], a[r4*4+1], a[r4*4+2], a[r4*4+3]);
  }
}
__device__ __forceinline__ void acc_add(const float* src, int lane, f32x16 acc[2][2]) {
  #pragma unroll
  for (int t = 0; t < 4; t++) {
    #pragma unroll
    for (int r4 = 0; r4 < 4; r4++) {
      float4 v = *(const float4*)(src + ((t * 4 + r4) * 64 + lane) * 4);
      acc[t>>1][t&1][r4*4]   += v.x;
      acc[t>>1][t&1][r4*4+1] += v.y;
      acc[t>>1][t&1][r4*4+2] += v.z;
      acc[t>>1][t&1][r4*4+3] += v.w;
    }
  }
}
// 8 waves -> 2 half-sums scattered as row*64+col into zone0 (red+8192) and
// zone1 (red+12288). All epilogues read two float4s and add (conflict-free).
__device__ __forceinline__ void reduce8(f32x16 acc[2][2], float* red, int lane, int wid) {
  if (wid >= 4) acc_wr(red + (size_t)(wid - 4) * 4096, lane, acc);
  __syncthreads();
  if (wid < 4) acc_add(red + (size_t)wid * 4096, lane, acc);
  if (wid == 2 || wid == 3) acc_wr(red + (size_t)wid * 4096, lane, acc);
  __syncthreads();
  if (wid < 2) {
    acc_add(red + (size_t)(wid + 2) * 4096, lane, acc);
    float* zone = red + 8192 + (size_t)wid * 4096;   // overwrites bufs 2,3 (safe: in-wave RAW order)
    #pragma unroll
    for (int ms = 0; ms < 2; ms++)
      #pragma unroll
      for (int ns = 0; ns < 2; ns++)
        #pragma unroll
        for (int rr = 0; rr < 16; rr++) {
          int row = ms * 32 + (rr & 3) + ((rr >> 2) << 3) + ((lane >> 5) << 2);
          zone[row * 64 + ns * 32 + (lane & 31)] = acc[ms][ns][rr];
        }
  }
  __syncthreads();
}
__device__ __forceinline__ float4 rsum4(const float* red, int row, int col) {
  float4 a = *(const float4*)&red[8192 + row * 64 + col];
  float4 b = *(const float4*)&red[12288 + row * 64 + col];
  return make_float4(a.x + b.x, a.y + b.y, a.z + b.z, a.w + b.w);
}

// ---------------- main persistent kernel (4 independent groups) ----------------
__global__ void __launch_bounds__(512, 2) kmain(const float* __restrict__ attn_v,
                                                const float* __restrict__ out_b,
                                                float* __restrict__ out) {
  __shared__ __align__(16) char asg[65536];  // ring-4: 4 chunk-slots x 8 waves x 2KB
  __shared__ float red[16384];               // 4 partial bufs / 2 result zones

  const half_t* x16 = WSCH(O_X16);
  const half_t* wL0 = WSCH(O_WL0);
  const half_t* wL1 = WSCH(O_WL1);
  const half_t* wP1 = WSCH(O_WP1);
  const half_t* wD0 = WSCH(O_WD0);
  const half_t* wD1 = WSCH(O_WD1);
  half_t* h0bB = WSH(O_H0B);
  half_t* h1bB = WSH(O_H1B);
  half_t* hd1  = WSH(O_HD1);
  half_t* h0d  = WSH(O_H0D);
  half_t* ctx  = WSH(O_CTX);
  half_t* eo   = WSH(O_EO);
  half_t* ep   = WSH(O_EP);
  float* c1 = WSF(O_C1);
  float* inp = WSF(O_INP);
  float* gates = WSF(O_GAT);

  const int tid = threadIdx.x;
  const int wid = tid >> 6;
  const int lane = tid & 63;
  const int g = blockIdx.x & 3;        // batch-slice group
  const int r = blockIdx.x >> 2;       // rank within group, 0..63
  const int sub = r & 1;
  const int m0 = g << 6;               // group's batch-row base
  const f32x16 zv = {0,0,0,0,0,0,0,0,0,0,0,0,0,0,0,0};
  int bstep = 0;

  // ================= encoder: 513 wavefront-pipelined steps =================
  {
    const bool isL1 = r >= 32;
    const int n0 = (r & 31) << 6;

    const half_t* wbase = isL1 ? (wL1 + (size_t)(n0 >> 6) * (8 * 8192))
                               : (wL0 + (size_t)(n0 >> 6) * (5 * 8192));
    const half_t* wb = wbase + (wid << 1) * 512 + lane * 8;
    const int ncB = isL1 ? 8 : 5;
    f16x8 B0[8], B1[8];
    #pragma unroll
    for (int c = 0; c < 8; c++) {
      if (c < ncB) {
        B0[c] = *(const f16x8*)(wb + (size_t)c * 8192);
        B1[c] = *(const f16x8*)(wb + (size_t)c * 8192 + 512);
      }
    }
    const int eu = tid & 15;
    const int ebl = tid >> 4;
    const float* bias = isL1 ? WSCF(O_BL1) : WSCF(O_BL0);
    float4 breg = *(const float4*)&bias[n0 + eu * 4];
    float creg0 = 0.f, creg1 = 0.f;

    for (int s = 0; s <= 512; s++) {
      const bool active = isL1 ? (s > 0) : (s < 512);
      if (active) {
        const half_t* h0r = h0bB + (size_t)((s + 1) & 1) * (256 * 512);
        f32x16 acc[2][2] = {{zv, zv}, {zv, zv}};
        int t;
        if (!isL1) {
          t = s;
          gemm_regB<5, 1, 0, 0>(Seg{x16, 128, t * 256 + m0}, Seg{h0r, 512, m0},
                                B0, B1, lane, wid, asg, acc);
        } else {
          t = s - 1;
          const half_t* h1r = h1bB + (size_t)(s & 1) * (256 * 512);
          gemm_regB<8, 4, 0, 0>(Seg{h0r, 512, m0}, Seg{h1r, 512, m0},
                                B0, B1, lane, wid, asg, acc);
        }
        reduce8(acc, red, lane, wid);
        half_t* hb = isL1 ? (h1bB + (size_t)((s - 1) & 1) * (256 * 512))
                          : (h0bB + (size_t)(s & 1) * (256 * 512));
        #pragma unroll
        for (int it = 0; it < 2; it++) {
          int bl = ebl + it * 32;
          float4 g4 = rsum4(red, bl, eu * 4);
          float gi = g4.x + breg.x, gf = g4.y + breg.y;
          float gz = g4.z + breg.z, go = g4.w + breg.w;
          float cold = it ? creg1 : creg0;
          float cn = fsig(gf) * cold + fsig(gi) * ftanh(gz);
          float hn = fsig(go) * ftanh(cn);
          if (it) creg1 = cn; else creg0 = cn;
          int bg = m0 + bl, ug = (n0 >> 2) + eu;
          stha(&hb[bg * 512 + ug], hn);                       // coherent publish
          if (isL1) eo[((size_t)bg * 512 + t) * 512 + ug] = (half_t)hn;  // plain
        }
      }
      gbarf(g, r, ++bstep);
    }

    if (isL1) {   // flush c-state (plain; covered by heavy barrier below)
      int ug = (n0 >> 2) + eu;
      c1[(m0 + ebl) * 512 + ug] = creg0;
      c1[(m0 + ebl + 32) * 512 + ug] = creg1;
    }
  }
  gbar_acq(g, sub);   // phase edge: flush eo + c1, invalidate stale L2

  // ====== enc_proj = enc_out @ attn_W^T (f16), group-local rows ======
  for (int j = 0; j < 64; j++) {
    const int jj = r * 64 + j;
    const int ml = jj >> 3;
    const int nt = jj & 7;
    const int row0 = (g << 15) + ml * 64;
    f32x16 acc[2][2] = {{zv, zv}, {zv, zv}};
    gemm_ks<4, 0, 0>(Seg{eo, 512, row0}, Seg{eo, 512, row0}, 4,
                     wP1 + (size_t)nt * (4 * 8192), lane, wid, asg, acc);
    reduce8(acc, red, lane, wid);
    {
      int row = tid >> 3, col = (tid & 7) * 8;
      float4 a0 = rsum4(red, row, col);
      float4 a1 = rsum4(red, row, col + 4);
      f16x8 h8;
      h8[0] = (half_t)a0.x; h8[1] = (half_t)a0.y; h8[2] = (half_t)a0.z; h8[3] = (half_t)a0.w;
      h8[4] = (half_t)a1.x; h8[5] = (half_t)a1.y; h8[6] = (half_t)a1.z; h8[7] = (half_t)a1.w;
      *(f16x8*)&ep[(size_t)(row0 + row) * 512 + nt * 64 + col] = h8;  // plain
    }
    __syncthreads();
  }
  gbar_acq(g, sub);   // phase edge: flush ep

  // ================= decoder: 30 steps (d=30 = final output-only pass) ======
  for (int d = 0; d <= 30; d++) {
    const half_t* hs = (d == 0) ? (h1bB + 256 * 512) : hd1;

    // ---- P1: h1 @ [attn_W | dWhh0 | out_W]: tiles 0..39 + 72, 1 GEMM/block --
    {
      const int jj = (r < 40) ? r : ((r == 63) ? 72 : -1);
      if (jj >= 0) {
        const int n0p = jj * 64;
        f32x16 acc[2][2] = {{zv, zv}, {zv, zv}};
        gemm_ks<4, 0, 0>(Seg{hs, 512, m0}, Seg{hs, 512, m0}, 4,
                         wP1 + (size_t)jj * (4 * 8192), lane, wid, asg, acc);
        reduce8(acc, red, lane, wid);
        if (n0p < 4608) {
          #pragma unroll
          for (int it = 0; it < 2; it++) {
            int q = it * 512 + tid;
            int row = q >> 4, col = (q & 15) * 4;
            float4 v4 = rsum4(red, row, col);
            float* dst = &gates[(size_t)(m0 + row) * 4672 + n0p + col];
            st64(dst, v4.x, v4.y);
            st64(dst + 2, v4.z, v4.w);
          }
        } else if (d > 0) {
          if (tid < 64) {
            int bg = m0 + tid;
            float v0 = red[8192 + tid * 64 + 0] + red[12288 + tid * 64 + 0] + out_b[0];
            float v1 = red[8192 + tid * 64 + 1] + red[12288 + tid * 64 + 1] + out_b[1];
            float v2 = red[8192 + tid * 64 + 2] + red[12288 + tid * 64 + 2] + out_b[2];
            out[(size_t)bg * 90 + (d - 1) * 3 + 0] = v0;
            out[(size_t)bg * 90 + (d - 1) * 3 + 1] = v1;
            out[(size_t)bg * 90 + (d - 1) * 3 + 2] = v2;
            stfa(&inp[bg], v1);
          }
        }
      }
    }
    gbarf(g, r, ++bstep);
    if (d == 30) break;

    // ---- P2: attention for batch row b = m0 + r ----
    {
      const int b = m0 + r;
      float* dpb = red;          // 512
      float* vb  = red + 512;    // 512
      float* eb  = red + 1024;   // 512
      float* ab2 = red + 2048;   // 512
      float* sc  = red + 2560;   // 16
      float* pm  = red + 4096;   // 8x512 ctx partials
      dpb[tid] = ldfa(&gates[(size_t)b * 4672 + tid]);
      vb[tid]  = attn_v[tid];
      __syncthreads();
      // hoist tt-invariant LDS reads into registers (were 16-way conflicted)
      float va[8], da[8];
      {
        float4 t0 = *(const float4*)&vb[lane * 8];
        float4 t1 = *(const float4*)&vb[lane * 8 + 4];
        float4 t2 = *(const float4*)&dpb[lane * 8];
        float4 t3 = *(const float4*)&dpb[lane * 8 + 4];
        va[0]=t0.x; va[1]=t0.y; va[2]=t0.z; va[3]=t0.w;
        va[4]=t1.x; va[5]=t1.y; va[6]=t1.z; va[7]=t1.w;
        da[0]=t2.x; da[1]=t2.y; da[2]=t2.z; da[3]=t2.w;
        da[4]=t3.x; da[5]=t3.y; da[6]=t3.z; da[7]=t3.w;
      }
      const half_t* eprow = ep + ((size_t)b << 18) + (size_t)(wid * 64) * 512 + lane * 8;
      for (int tt = 0; tt < 64; tt++) {
        f16x8 e8 = *(const f16x8*)(eprow + (size_t)tt * 512);
        float sum = 0.f;
        #pragma unroll
        for (int jq = 0; jq < 8; jq++)
          sum += va[jq] * ftanh((float)e8[jq] + da[jq]);
        #pragma unroll
        for (int off = 32; off > 0; off >>= 1) sum += __shfl_down(sum, off, 64);
        if (lane == 0) eb[wid * 64 + tt] = sum;
      }
      __syncthreads();
      float e0 = eb[tid];
      float mx = e0;
      #pragma unroll
      for (int off = 32; off > 0; off >>= 1) mx = fmaxf(mx, __shfl_xor(mx, off, 64));
      if (lane == 0) sc[wid] = mx;
      __syncthreads();
      mx = sc[0];
      #pragma unroll
      for (int q = 1; q < 8; q++) mx = fmaxf(mx, sc[q]);
      float x0 = __expf(e0 - mx);
      float ssum = x0;
      #pragma unroll
      for (int off = 32; off > 0; off >>= 1) ssum += __shfl_xor(ssum, off, 64);
      __syncthreads();
      if (lane == 0) sc[8 + wid] = ssum;
      __syncthreads();
      float tot = sc[8];
      #pragma unroll
      for (int q = 1; q < 8; q++) tot += sc[8 + q];
      float inv = 1.f / tot;
      ab2[tid] = x0 * inv;
      __syncthreads();
      float pacc[8] = {0,0,0,0,0,0,0,0};
      const half_t* eow = eo + ((size_t)b << 18) + (size_t)(wid * 64) * 512 + lane * 8;
      for (int tt = 0; tt < 64; tt++) {
        f16x8 h8 = *(const f16x8*)(eow + (size_t)tt * 512);
        float at = ab2[wid * 64 + tt];
        #pragma unroll
        for (int jq = 0; jq < 8; jq++) pacc[jq] += at * (float)h8[jq];
      }
      #pragma unroll
      for (int jq = 0; jq < 8; jq++) pm[wid * 512 + lane * 8 + jq] = pacc[jq];
      __syncthreads();
      float sctx = 0.f;
      #pragma unroll
      for (int w = 0; w < 8; w++) sctx += pm[w * 512 + tid];
      stha(&ctx[(b << 9) + tid], sctx);                          // coherent
    }
    gbarf(g, r, ++bstep);

    // ---- P3: r<32: gates0 = ctx @ dWih0[:,1:] + inp*w0col + partial -> h0d
    //          r>=32: dWhh1 partial tiles 40..71 (moved from P1; hs stable) ---
    if (r < 32) {
      const int n0 = r << 6;
      f32x16 acc[2][2] = {{zv, zv}, {zv, zv}};
      gemm_ks<4, 0, 0>(Seg{ctx, 512, m0}, Seg{ctx, 512, m0}, 4,
                       wD0 + (size_t)(n0 >> 6) * (4 * 8192), lane, wid, asg, acc);
      reduce8(acc, red, lane, wid);
      const float* bD0 = WSCF(O_BD0);
      const float* w0c = WSCF(O_W0C);
      #pragma unroll
      for (int it = 0; it < 2; it++) {
        int q = it * 512 + tid;
        int u = q & 15, bl = q >> 4;
        int bg = m0 + bl, ug = (n0 >> 2) + u, nl = n0 + u * 4;
        float4 g4 = rsum4(red, bl, u * 4);
        float p0, p1, p2, p3;
        ld64(&gates[(size_t)bg * 4672 + 512 + nl], p0, p1);
        ld64(&gates[(size_t)bg * 4672 + 512 + nl + 2], p2, p3);
        float4 b4 = *(const float4*)&bD0[nl];
        float4 w4 = *(const float4*)&w0c[nl];
        float iv = ldfa(&inp[bg]);
        float gi = g4.x + p0 + b4.x + iv * w4.x;
        float gf = g4.y + p1 + b4.y + iv * w4.y;
        float gz = g4.z + p2 + b4.z + iv * w4.z;
        float go = g4.w + p3 + b4.w + iv * w4.w;
        float cold = c1[bg * 512 + ug];
        float cn = fsig(gf) * cold + fsig(gi) * ftanh(gz);
        stha(&h0d[bg * 512 + ug], fsig(go) * ftanh(cn));        // coherent
      }
    } else {
      const int jj = 8 + r;                 // r=32..63 -> tiles 40..71
      const int n0p = jj * 64;
      f32x16 acc[2][2] = {{zv, zv}, {zv, zv}};
      gemm_ks<4, 0, 0>(Seg{hs, 512, m0}, Seg{hs, 512, m0}, 4,
                       wP1 + (size_t)jj * (4 * 8192), lane, wid, asg, acc);
      reduce8(acc, red, lane, wid);
      #pragma unroll
      for (int it = 0; it < 2; it++) {
        int q = it * 512 + tid;
        int row = q >> 4, col = (q & 15) * 4;
        float4 v4 = rsum4(red, row, col);
        float* dst = &gates[(size_t)(m0 + row) * 4672 + n0p + col];
        st64(dst, v4.x, v4.y);
        st64(dst + 2, v4.z, v4.w);
      }
    }
    gbarf(g, r, ++bstep);

    // ---- P4: gates1 = h0d @ dWih1 + partial + bias -> c1, hd1 ----
    if (r < 32) {
      const int n0 = r << 6;
      f32x16 acc[2][2] = {{zv, zv}, {zv, zv}};
      gemm_ks<4, 0, 0>(Seg{h0d, 512, m0}, Seg{h0d, 512, m0}, 4,
                       wD1 + (size_t)(n0 >> 6) * (4 * 8192), lane, wid, asg, acc);
      reduce8(acc, red, lane, wid);
      const float* bD1 = WSCF(O_BD1);
      #pragma unroll
      for (int it = 0; it < 2; it++) {
        int q = it * 512 + tid;
        int u = q & 15, bl = q >> 4;
        int bg = m0 + bl, ug = (n0 >> 2) + u, nl = n0 + u * 4;
        float4 g4 = rsum4(red, bl, u * 4);
        float p0, p1, p2, p3;
        ld64(&gates[(size_t)bg * 4672 + 2560 + nl], p0, p1);
        ld64(&gates[(size_t)bg * 4672 + 2560 + nl + 2], p2, p3);
        float4 b4 = *(const float4*)&bD1[nl];
        float gi = g4.x + p0 + b4.x;
        float gf = g4.y + p1 + b4.y;
        float gz = g4.z + p2 + b4.z;
        float go = g4.w + p3 + b4.w;
        float cold = c1[bg * 512 + ug];
        float cn = fsig(gf) * cold + fsig(gi) * ftanh(gz);
        float hn = fsig(go) * ftanh(cn);
        c1[bg * 512 + ug] = cn;                                  // self-read only
        stha(&hd1[bg * 512 + ug], hn);                           // coherent
      }
    }
    gbarf(g, r, ++bstep);
  }
}

// ---------------- prep kernels ----------------
__global__ void kpackB(size_t dstOff, int id, int Ntiles, int NC,
                       const float* s0, const float* s1,
                       const float* s2, const float* s3) {
  half_t* dst = (half_t*)(g_ws + dstOff);
  size_t total = (size_t)Ntiles * NC * 8192;
  size_t i = (size_t)blockIdx.x * 256 + threadIdx.x;
  size_t stride = (size_t)gridDim.x * 256;
  for (size_t e = i; e < total; e += stride) {
    int j = e & 7;
    int l = (e >> 3) & 63;
    int bh = (e >> 9) & 1;
    int w = (e >> 10) & 7;
    int tc = (int)(e >> 13);
    int c = tc % NC;
    int tile = tc / NC;
    int n = tile * 64 + bh * 32 + (l & 31);
    int k = c * 128 + w * 16 + ((l >> 5) << 3) + j;
    float v = 0.f;
    if (id == 0) {          // wL0: [Wih0(64) | pad(64) | Whh0(512)]
      int pn = gperm(n);
      if (k < 64) v = s0[(size_t)pn * 64 + k];
      else if (k >= 128) v = s1[(size_t)pn * 512 + (k - 128)];
    } else if (id == 1) {   // wL1: [Wih1(512) | Whh1(512)]
      int pn = gperm(n);
      v = (k < 512) ? s0[(size_t)pn * 512 + k] : s1[(size_t)pn * 512 + (k - 512)];
    } else if (id == 2) {   // wP1: [attnW | dWhh0 | dWhh1 | outW | pad]
      if (n < 512) v = s0[((size_t)n << 9) + k];
      else if (n < 2560) v = s1[((size_t)gperm(n - 512) << 9) + k];
      else if (n < 4608) v = s2[((size_t)gperm(n - 2560) << 9) + k];
      else if (n < 4611) v = s3[((size_t)(n - 4608) << 9) + k];
    } else if (id == 3) {   // wD0: dec_Wih0[:,1:]
      v = s0[(size_t)gperm(n) * 513 + 1 + k];
    } else {                // wD1
      v = s0[((size_t)gperm(n) << 9) + k];
    }
    dst[e] = (half_t)v;
  }
}

__global__ void kmisc(const float* ebih0, const float* ebhh0, const float* ebih1, const float* ebhh1,
                      const float* dbih0, const float* dbhh0, const float* dbih1, const float* dbhh1,
                      const float* dWih0, const float* x) {
  float* bL0 = WSF(O_BL0);
  float* bL1 = WSF(O_BL1);
  float* bD0 = WSF(O_BD0);
  float* bD1 = WSF(O_BD1);
  float* w0c = WSF(O_W0C);
  half_t* h0b = WSH(O_H0B);
  half_t* h1b = WSH(O_H1B);
  float* c1 = WSF(O_C1);
  float* inp = WSF(O_INP);
  int i = blockIdx.x * 256 + threadIdx.x, stride = gridDim.x * 256;
  for (int idx = i; idx < 262144; idx += stride) {
    if (idx < 2048) {
      int pn = gperm(idx);
      bL0[idx] = ebih0[pn] + ebhh0[pn];
      bL1[idx] = ebih1[pn] + ebhh1[pn];
      bD0[idx] = dbih0[pn] + dbhh0[pn];
      bD1[idx] = dbih1[pn] + dbhh1[pn];
      w0c[idx] = dWih0[(size_t)pn * 513];
      g_bar[idx] = 0;
    }
    if (idx < 1024) g_flags[idx] = 0;
    if (idx < 256) inp[idx] = x[((size_t)idx * 512 + 511) * 64];
    h0b[idx] = (half_t)0.f;
    h1b[idx] = (half_t)0.f;
    if (idx < 131072) c1[idx] = 0.f;
  }
}

__global__ void kx16(const float* x) {
  half_t* dst = WSH(O_X16);   // (t, b, 128) zero-padded cols 64..127
  size_t i = (size_t)blockIdx.x * 256 + threadIdx.x;
  size_t stride = (size_t)gridDim.x * 256;
  for (size_t e = i; e < (size_t)512 * 256 * 128; e += stride) {
    int t = (int)(e >> 15);
    int b = (int)((e >> 7) & 255);
    int ii = (int)(e & 127);
    dst[e] = (ii < 64) ? (half_t)x[((size_t)b * 512 + t) * 64 + ii] : (half_t)0.f;
  }
}

// ---------------- launch ----------------
extern "C" void kernel_launch(void* const* d_in, const int* in_sizes, int n_in,
                              void* d_out, int out_size, void* d_ws, size_t ws_size,
                              hipStream_t stream) {
  const float* x     = (const float*)d_in[0];
  const float* eWih0 = (const float*)d_in[1];
  const float* eWhh0 = (const float*)d_in[2];
  const float* ebih0 = (const float*)d_in[3];
  const float* ebhh0 = (const float*)d_in[4];
  const float* eWih1 = (const float*)d_in[5];
  const float* eWhh1 = (const float*)d_in[6];
  const float* ebih1 = (const float*)d_in[7];
  const float* ebhh1 = (const float*)d_in[8];
  const float* dWih0 = (const float*)d_in[9];
  const float* dWhh0 = (const float*)d_in[10];
  const float* dbih0 = (const float*)d_in[11];
  const float* dbhh0 = (const float*)d_in[12];
  const float* dWih1 = (const float*)d_in[13];
  const float* dWhh1 = (const float*)d_in[14];
  const float* dbih1 = (const float*)d_in[15];
  const float* dbhh1 = (const float*)d_in[16];
  const float* attnW = (const float*)d_in[17];
  const float* attnv = (const float*)d_in[18];
  const float* outW  = (const float*)d_in[19];
  const float* outb  = (const float*)d_in[20];
  (void)in_sizes; (void)n_in; (void)out_size; (void)d_ws; (void)ws_size;

  kpackB<<<1024, 256, 0, stream>>>(O_WL0, 0, 32, 5, eWih0, eWhh0, nullptr, nullptr);
  kpackB<<<1024, 256, 0, stream>>>(O_WL1, 1, 32, 8, eWih1, eWhh1, nullptr, nullptr);
  kpackB<<<1024, 256, 0, stream>>>(O_WP1, 2, 73, 4, attnW, dWhh0, dWhh1, outW);
  kpackB<<<1024, 256, 0, stream>>>(O_WD0, 3, 32, 4, dWih0, nullptr, nullptr, nullptr);
  kpackB<<<1024, 256, 0, stream>>>(O_WD1, 4, 32, 4, dWih1, nullptr, nullptr, nullptr);
  kmisc<<<1024, 256, 0, stream>>>(ebih0, ebhh0, ebih1, ebhh1,
                                  dbih0, dbhh0, dbih1, dbhh1, dWih0, x);
  kx16<<<2048, 256, 0, stream>>>(x);

  float* outp = (float*)d_out;
  void* args[] = {(void*)&attnv, (void*)&outb, (void*)&outp};
  hipError_t e = hipLaunchCooperativeKernel((void*)kmain, dim3(256), dim3(512),
                                            args, 0, stream);
  if (e != hipSuccess) {
    kmain<<<dim3(256), dim3(512), 0, stream>>>(attnv, outb, outp);
  }
}

// Round 2
// 8580.405 us; speedup vs baseline: 1.0501x; 1.0501x over previous
//
#include <hip/hip_runtime.h>

// ---------------------------------------------------------------------------
// Seq2Seq LSTM + attention, persistent kernel for MI355X (gfx950)
// B=256, T=512, I=64, H=512, HORIZON=30, NQ=3
// R9: revert R8's cached-load+buffer_inv scheme (regressed: per-barrier L2
// invalidate defeated all reuse and cost ~0.7us x 640 barriers). Back to R7
// coherence: sc0|sc1 write-through stores + AUXC (bypass L1/L2) loads, no
// fence in gbarf. KEPT from R8: decoder rebalance (P1 = tiles 0..39 + out
// tile, dWhh1 tiles 40..71 in P3's idle r>=32 half). NEW: encoder staging
// ring deepened 4->5 slots (80KB asg, 147KB LDS total) - 5 chunks in flight
// instead of 3; L0 stages its whole A upfront.
// Carried from R7: conflict-free 3-sync K-split reduction, flag-vote group
// barrier, P2 LDS reads hoisted to registers, weights in registers (encoder).
// ---------------------------------------------------------------------------

typedef _Float16 half_t;
typedef __attribute__((ext_vector_type(8)))  _Float16 f16x8;
typedef __attribute__((ext_vector_type(16))) float    f32x16;

#define MFMA(a,b,c) __builtin_amdgcn_mfma_f32_32x32x16_f16((a),(b),(c),0,0,0)
#define CBAR()      asm volatile("" ::: "memory")
#define AUXC 17   // CPol SC0|SC1: agent-coherent (bypass stale L1/L2)

template<int N> __device__ __forceinline__ void waitvm() {
  asm volatile("s_waitcnt vmcnt(%0)" :: "n"(N) : "memory");
}

__device__ __forceinline__ float fsig(float x)  { return 1.0f / (1.0f + __expf(-x)); }
__device__ __forceinline__ float ftanh(float x) { return 1.0f - 2.0f / (1.0f + __expf(2.0f * x)); }

// ---------------- coherent scalar ops (agent scope, relaxed) ----------------
union FU { float f; unsigned u; };
union HU { _Float16 h; unsigned short u; };
__device__ __forceinline__ float ldfa(const float* p) {
  unsigned v = __hip_atomic_load((const unsigned*)p, __ATOMIC_RELAXED, __HIP_MEMORY_SCOPE_AGENT);
  FU c; c.u = v; return c.f;
}
__device__ __forceinline__ void stfa(float* p, float v) {
  FU c; c.f = v;
  __hip_atomic_store((unsigned*)p, c.u, __ATOMIC_RELAXED, __HIP_MEMORY_SCOPE_AGENT);
}
__device__ __forceinline__ void stha(half_t* p, float v) {
  HU c; c.h = (half_t)v;
  __hip_atomic_store((unsigned short*)p, c.u, __ATOMIC_RELAXED, __HIP_MEMORY_SCOPE_AGENT);
}
__device__ __forceinline__ void st64(float* p, float a, float b) {
  FU x, y; x.f = a; y.f = b;
  unsigned long long v = (unsigned long long)x.u | ((unsigned long long)y.u << 32);
  __hip_atomic_store((unsigned long long*)p, v, __ATOMIC_RELAXED, __HIP_MEMORY_SCOPE_AGENT);
}
__device__ __forceinline__ void ld64(const float* p, float& a, float& b) {
  unsigned long long v = __hip_atomic_load((const unsigned long long*)p, __ATOMIC_RELAXED, __HIP_MEMORY_SCOPE_AGENT);
  FU x, y; x.u = (unsigned)v; y.u = (unsigned)(v >> 32); a = x.f; b = y.f;
}

// ---------------- workspace layout (bytes, inside g_ws) ----------------
static constexpr size_t O_X16 = 0;                             // (T,B,128) f16 x zero-padded
static constexpr size_t O_WL0 = O_X16 + (size_t)512*256*128*2; // 32t x 5c packed  (2048x640)
static constexpr size_t O_WL1 = O_WL0 + (size_t)2048*640*2;    // 32t x 8c packed  (2048x1024)
static constexpr size_t O_WP1 = O_WL1 + (size_t)2048*1024*2;   // 73t x 4c packed  (4672x512)
static constexpr size_t O_WD0 = O_WP1 + (size_t)4672*512*2;    // 32t x 4c packed
static constexpr size_t O_WD1 = O_WD0 + (size_t)2048*512*2;    // 32t x 4c packed
static constexpr size_t O_BL0 = O_WD1 + (size_t)2048*512*2;    // 2048 f32 biases (gate-permuted)
static constexpr size_t O_BL1 = O_BL0 + 8192;
static constexpr size_t O_BD0 = O_BL1 + 8192;
static constexpr size_t O_BD1 = O_BD0 + 8192;
static constexpr size_t O_W0C = O_BD1 + 8192;                  // 2048 f32 dec_Wih0[:,0] permuted
static constexpr size_t O_H0B = O_W0C + 8192;                  // 2 x (256,512) f16 L0 h ping-pong
static constexpr size_t O_H1B = O_H0B + (size_t)2*256*512*2;   // 2 x (256,512) f16 L1 h ping-pong
static constexpr size_t O_HD1 = O_H1B + (size_t)2*256*512*2;   // (256,512) f16 decoder h1
static constexpr size_t O_H0D = O_HD1 + (size_t)256*512*2;     // (256,512) f16 decoder h0
static constexpr size_t O_CTX = O_H0D + (size_t)256*512*2;     // (256,512) f16 context
static constexpr size_t O_C0  = O_CTX + (size_t)256*512*2;     // (256,512) f32 (unused scratch)
static constexpr size_t O_C1  = O_C0  + (size_t)256*512*4;     // (256,512) f32
static constexpr size_t O_INP = O_C1  + (size_t)256*512*4;     // 256 f32
static constexpr size_t O_GAT = O_INP + 1024;                  // (256,4672) f32 gate partials
static constexpr size_t O_EO  = O_GAT + (size_t)256*4672*4;    // (B*T,H) f16 encoder outputs
static constexpr size_t O_EP  = O_EO  + (size_t)256*512*512*2; // (B*T,512) f16 enc_proj
static constexpr size_t WS_NEED = O_EP + (size_t)256*512*512*2;

__device__ __align__(4096) unsigned char g_ws[WS_NEED];
__device__ int g_bar[2048];    // acq/rel barrier lines (phase edges)
__device__ int g_flags[1024];  // 4 groups x 64 block flags

#define WSH(o) ((half_t*)(g_ws + (o)))
#define WSCH(o) ((const half_t*)(g_ws + (o)))
#define WSF(o) ((float*)(g_ws + (o)))
#define WSCF(o) ((const float*)(g_ws + (o)))
#define BLINE(i) (g_bar + ((size_t)(i) << 5))

__device__ __forceinline__ int gperm(int n) { return (n & 3) * 512 + (n >> 2); }

// ------- flag-vote group barrier: zero-contention arrive, ballot poll -------
// Block (g,r) stores flags[g*64+r]=step; wave 0 polls all 64 flags until all
// >= step. No RMWs, no master chain. Data coherence is carried by the sc0|sc1
// stores (drained at the syncthreads' vmcnt(0)) + AUXC loads, not the barrier.
__device__ __forceinline__ void gbarf(int g, int r, int step) {
  __syncthreads();   // drains vmcnt(0): all coherent stores are L3-visible
  if (threadIdx.x < 64) {
    if (threadIdx.x == 0)
      __hip_atomic_store(&g_flags[(g << 6) + r], step,
                         __ATOMIC_RELAXED, __HIP_MEMORY_SCOPE_AGENT);
    const int* fp = &g_flags[(g << 6) + threadIdx.x];
    for (;;) {
      int v = __hip_atomic_load(fp, __ATOMIC_RELAXED, __HIP_MEMORY_SCOPE_AGENT);
      if (__all(v >= step)) break;
      __builtin_amdgcn_s_sleep(1);
    }
  }
  __syncthreads();
}

// Heavy barrier: full release (L2 writeback) / acquire (L2 inv) — phase edges.
__device__ __forceinline__ void gbar_acq(int g, int sub) {
  __syncthreads();
  if (threadIdx.x == 0) {
    int* cnt = BLINE(g * 2 + sub);
    int* mst = BLINE(8 + g);
    int* gs  = BLINE(12 + g * 2 + sub);
    int old = __hip_atomic_load(gs, __ATOMIC_RELAXED, __HIP_MEMORY_SCOPE_AGENT);
    int a = __hip_atomic_fetch_add(cnt, 1, __ATOMIC_ACQ_REL, __HIP_MEMORY_SCOPE_AGENT);
    if (a == 31) {
      __hip_atomic_store(cnt, 0, __ATOMIC_RELAXED, __HIP_MEMORY_SCOPE_AGENT);
      int m = __hip_atomic_fetch_add(mst, 1, __ATOMIC_ACQ_REL, __HIP_MEMORY_SCOPE_AGENT);
      if (m == 1) {
        __hip_atomic_store(mst, 0, __ATOMIC_RELAXED, __HIP_MEMORY_SCOPE_AGENT);
        __hip_atomic_fetch_add(BLINE(12 + g * 2), 1, __ATOMIC_RELEASE, __HIP_MEMORY_SCOPE_AGENT);
        __hip_atomic_fetch_add(BLINE(12 + g * 2 + 1), 1, __ATOMIC_RELEASE, __HIP_MEMORY_SCOPE_AGENT);
      }
    }
    while (__hip_atomic_load(gs, __ATOMIC_RELAXED, __HIP_MEMORY_SCOPE_AGENT) == old)
      __builtin_amdgcn_s_sleep(2);
    (void)__hip_atomic_load(gs, __ATOMIC_ACQUIRE, __HIP_MEMORY_SCOPE_AGENT);
  }
  __syncthreads();
}

// ---------------- GEMM cores: 64x64 tile, K-split over 8 waves (chunk=128) ---
struct Seg { const half_t* p; int stride; int row0; };

template<int AXA, int AXB>
__device__ __forceinline__ void stageA(Seg sa, Seg sb, int cSplit, int c,
                                       int lane, int wid, char* dst) {
  bool isA = c < cSplit;
  Seg s = isA ? sa : sb;
  int kb = (isA ? c : (c - cSplit)) * 128;
  const half_t* g = s.p + (size_t)(s.row0 + (lane & 31)) * s.stride
                        + kb + (wid << 4) + ((lane >> 5) << 3);
  if (isA) {
    __builtin_amdgcn_global_load_lds(
        (const __attribute__((address_space(1))) unsigned int*)g,
        (__attribute__((address_space(3))) unsigned int*)dst, 16, 0, AXA);
    __builtin_amdgcn_global_load_lds(
        (const __attribute__((address_space(1))) unsigned int*)(g + (size_t)32 * s.stride),
        (__attribute__((address_space(3))) unsigned int*)(dst + 1024), 16, 0, AXA);
  } else {
    __builtin_amdgcn_global_load_lds(
        (const __attribute__((address_space(1))) unsigned int*)g,
        (__attribute__((address_space(3))) unsigned int*)dst, 16, 0, AXB);
    __builtin_amdgcn_global_load_lds(
        (const __attribute__((address_space(1))) unsigned int*)(g + (size_t)32 * s.stride),
        (__attribute__((address_space(3))) unsigned int*)(dst + 1024), 16, 0, AXB);
  }
}

// ---- encoder K-body: B in registers, ring-5 staged A (5 chunks in flight) ----
template<int C, int NC, int CSPLIT, int AXA, int AXB>
__device__ __forceinline__ void kreg(Seg sa, Seg sb,
                                     const f16x8 (&B0)[8], const f16x8 (&B1)[8],
                                     int lane, int wid, char* asg, f32x16 acc[2][2]) {
  if constexpr (C < NC) {
    constexpr int rem = NC - 1 - C;
    waitvm<2 * (rem < 4 ? rem : 4)>();
    char* ab = asg + (size_t)(((C % 5) * 8 + wid)) * 2048 + lane * 16;
    f16x8 a0 = *(const f16x8*)ab;
    f16x8 a1 = *(const f16x8*)(ab + 1024);
    acc[0][0] = MFMA(a0, B0[C], acc[0][0]);
    acc[0][1] = MFMA(a0, B1[C], acc[0][1]);
    acc[1][0] = MFMA(a1, B0[C], acc[1][0]);
    acc[1][1] = MFMA(a1, B1[C], acc[1][1]);
    if constexpr (C + 5 < NC)
      stageA<AXA, AXB>(sa, sb, CSPLIT, C + 5, lane, wid,
                       asg + (size_t)((((C + 5) % 5) * 8 + wid)) * 2048);
    CBAR();
    kreg<C + 1, NC, CSPLIT, AXA, AXB>(sa, sb, B0, B1, lane, wid, asg, acc);
  }
}

template<int NC, int CSPLIT, int AXA, int AXB>
__device__ __forceinline__ void gemm_regB(Seg sa, Seg sb,
                                          const f16x8 (&B0)[8], const f16x8 (&B1)[8],
                                          int lane, int wid, char* asg, f32x16 acc[2][2]) {
  #pragma unroll
  for (int c = 0; c < (NC < 5 ? NC : 5); c++) {
    stageA<AXA, AXB>(sa, sb, CSPLIT, c, lane, wid, asg + (size_t)(c * 8 + wid) * 2048);
    CBAR();
  }
  kreg<0, NC, CSPLIT, AXA, AXB>(sa, sb, B0, B1, lane, wid, asg, acc);
}

// ---- streamed-B K-body (NC<=4): all chunks issued upfront ----
template<int C, int NC>
__device__ __forceinline__ void kks(int lane, int wid, char* asg, f32x16 acc[2][2],
                                    f16x8 (&b0)[4], f16x8 (&b1)[4]) {
  if constexpr (C < NC) {
    waitvm<4 * (NC - 1 - C)>();
    char* ab = asg + (size_t)(C * 8 + wid) * 2048 + lane * 16;
    f16x8 a0 = *(const f16x8*)ab;
    f16x8 a1 = *(const f16x8*)(ab + 1024);
    acc[0][0] = MFMA(a0, b0[C], acc[0][0]);
    acc[0][1] = MFMA(a0, b1[C], acc[0][1]);
    acc[1][0] = MFMA(a1, b0[C], acc[1][0]);
    acc[1][1] = MFMA(a1, b1[C], acc[1][1]);
    CBAR();
    kks<C + 1, NC>(lane, wid, asg, acc, b0, b1);
  }
}

template<int NC, int AXA, int AXB>
__device__ __forceinline__ void gemm_ks(Seg sa, Seg sb, int cSplit, const half_t* Wt,
                                        int lane, int wid, char* asg, f32x16 acc[2][2]) {
  const half_t* wb = Wt + (wid << 1) * 512 + lane * 8;
  f16x8 b0[4], b1[4];
  #pragma unroll
  for (int c = 0; c < NC; c++) {
    stageA<AXA, AXB>(sa, sb, cSplit, c, lane, wid, asg + (size_t)(c * 8 + wid) * 2048);
    CBAR();
    b0[c] = *(const f16x8*)(wb + (size_t)c * 8192);
    b1[c] = *(const f16x8*)(wb + (size_t)c * 8192 + 512);
    CBAR();
  }
  kks<0, NC>(lane, wid, asg, acc, b0, b1);
}

// ---------------- K-split reduction: 3 syncs, conflict-free ------------------
__device__ __forceinline__ void acc_wr(float* dst, int lane, f32x16 acc[2][2]) {
  #pragma unroll
  for (int t = 0; t < 4; t++) {
    f32x16 a = acc[t >> 1][t & 1];
    #pragma unroll
    for (int r4 = 0; r4 < 4; r4++)
      *(float4*)(dst + ((t * 4 + r4) * 64 + lane) * 4) =
          make_float4(a[r4*4], a[r4*4+1], a[r4*4+2], a[r4*4+3]);
  }
}
__device__ __forceinline__ void acc_add(const float* src, int lane, f32x16 acc[2][2]) {
  #pragma unroll
  for (int t = 0; t < 4; t++) {
    #pragma unroll
    for (int r4 = 0; r4 < 4; r4++) {
      float4 v = *(const float4*)(src + ((t * 4 + r4) * 64 + lane) * 4);
      acc[t>>1][t&1][r4*4]   += v.x;
      acc[t>>1][t&1][r4*4+1] += v.y;
      acc[t>>1][t&1][r4*4+2] += v.z;
      acc[t>>1][t&1][r4*4+3] += v.w;
    }
  }
}
// 8 waves -> 2 half-sums scattered as row*64+col into zone0 (red+8192) and
// zone1 (red+12288). All epilogues read two float4s and add (conflict-free).
__device__ __forceinline__ void reduce8(f32x16 acc[2][2], float* red, int lane, int wid) {
  if (wid >= 4) acc_wr(red + (size_t)(wid - 4) * 4096, lane, acc);
  __syncthreads();
  if (wid < 4) acc_add(red + (size_t)wid * 4096, lane, acc);
  if (wid == 2 || wid == 3) acc_wr(red + (size_t)wid * 4096, lane, acc);
  __syncthreads();
  if (wid < 2) {
    acc_add(red + (size_t)(wid + 2) * 4096, lane, acc);
    float* zone = red + 8192 + (size_t)wid * 4096;   // overwrites bufs 2,3 (safe: in-wave RAW order)
    #pragma unroll
    for (int ms = 0; ms < 2; ms++)
      #pragma unroll
      for (int ns = 0; ns < 2; ns++)
        #pragma unroll
        for (int rr = 0; rr < 16; rr++) {
          int row = ms * 32 + (rr & 3) + ((rr >> 2) << 3) + ((lane >> 5) << 2);
          zone[row * 64 + ns * 32 + (lane & 31)] = acc[ms][ns][rr];
        }
  }
  __syncthreads();
}
__device__ __forceinline__ float4 rsum4(const float* red, int row, int col) {
  float4 a = *(const float4*)&red[8192 + row * 64 + col];
  float4 b = *(const float4*)&red[12288 + row * 64 + col];
  return make_float4(a.x + b.x, a.y + b.y, a.z + b.z, a.w + b.w);
}

// ---------------- main persistent kernel (4 independent groups) ----------------
__global__ void __launch_bounds__(512, 2) kmain(const float* __restrict__ attn_v,
                                                const float* __restrict__ out_b,
                                                float* __restrict__ out) {
  __shared__ __align__(16) char asg[81920];  // ring-5: 5 chunk-slots x 8 waves x 2KB
  __shared__ float red[16384];               // 4 partial bufs / 2 result zones

  const half_t* x16 = WSCH(O_X16);
  const half_t* wL0 = WSCH(O_WL0);
  const half_t* wL1 = WSCH(O_WL1);
  const half_t* wP1 = WSCH(O_WP1);
  const half_t* wD0 = WSCH(O_WD0);
  const half_t* wD1 = WSCH(O_WD1);
  half_t* h0bB = WSH(O_H0B);
  half_t* h1bB = WSH(O_H1B);
  half_t* hd1  = WSH(O_HD1);
  half_t* h0d  = WSH(O_H0D);
  half_t* ctx  = WSH(O_CTX);
  half_t* eo   = WSH(O_EO);
  half_t* ep   = WSH(O_EP);
  float* c1 = WSF(O_C1);
  float* inp = WSF(O_INP);
  float* gates = WSF(O_GAT);

  const int tid = threadIdx.x;
  const int wid = tid >> 6;
  const int lane = tid & 63;
  const int g = blockIdx.x & 3;        // batch-slice group
  const int r = blockIdx.x >> 2;       // rank within group, 0..63
  const int sub = r & 1;
  const int m0 = g << 6;               // group's batch-row base
  const f32x16 zv = {0,0,0,0,0,0,0,0,0,0,0,0,0,0,0,0};
  int bstep = 0;

  // ================= encoder: 513 wavefront-pipelined steps =================
  {
    const bool isL1 = r >= 32;
    const int n0 = (r & 31) << 6;

    const half_t* wbase = isL1 ? (wL1 + (size_t)(n0 >> 6) * (8 * 8192))
                               : (wL0 + (size_t)(n0 >> 6) * (5 * 8192));
    const half_t* wb = wbase + (wid << 1) * 512 + lane * 8;
    const int ncB = isL1 ? 8 : 5;
    f16x8 B0[8], B1[8];
    #pragma unroll
    for (int c = 0; c < 8; c++) {
      if (c < ncB) {
        B0[c] = *(const f16x8*)(wb + (size_t)c * 8192);
        B1[c] = *(const f16x8*)(wb + (size_t)c * 8192 + 512);
      }
    }
    const int eu = tid & 15;
    const int ebl = tid >> 4;
    const float* bias = isL1 ? WSCF(O_BL1) : WSCF(O_BL0);
    float4 breg = *(const float4*)&bias[n0 + eu * 4];
    float creg0 = 0.f, creg1 = 0.f;

    for (int s = 0; s <= 512; s++) {
      const bool active = isL1 ? (s > 0) : (s < 512);
      if (active) {
        const half_t* h0r = h0bB + (size_t)((s + 1) & 1) * (256 * 512);
        f32x16 acc[2][2] = {{zv, zv}, {zv, zv}};
        int t;
        if (!isL1) {
          t = s;
          gemm_regB<5, 1, 0, AUXC>(Seg{x16, 128, t * 256 + m0}, Seg{h0r, 512, m0},
                                   B0, B1, lane, wid, asg, acc);
        } else {
          t = s - 1;
          const half_t* h1r = h1bB + (size_t)(s & 1) * (256 * 512);
          gemm_regB<8, 4, AUXC, AUXC>(Seg{h0r, 512, m0}, Seg{h1r, 512, m0},
                                      B0, B1, lane, wid, asg, acc);
        }
        reduce8(acc, red, lane, wid);
        half_t* hb = isL1 ? (h1bB + (size_t)((s - 1) & 1) * (256 * 512))
                          : (h0bB + (size_t)(s & 1) * (256 * 512));
        #pragma unroll
        for (int it = 0; it < 2; it++) {
          int bl = ebl + it * 32;
          float4 g4 = rsum4(red, bl, eu * 4);
          float gi = g4.x + breg.x, gf = g4.y + breg.y;
          float gz = g4.z + breg.z, go = g4.w + breg.w;
          float cold = it ? creg1 : creg0;
          float cn = fsig(gf) * cold + fsig(gi) * ftanh(gz);
          float hn = fsig(go) * ftanh(cn);
          if (it) creg1 = cn; else creg0 = cn;
          int bg = m0 + bl, ug = (n0 >> 2) + eu;
          stha(&hb[bg * 512 + ug], hn);                       // coherent publish
          if (isL1) eo[((size_t)bg * 512 + t) * 512 + ug] = (half_t)hn;  // plain
        }
      }
      gbarf(g, r, ++bstep);
    }

    if (isL1) {   // flush c-state (plain; covered by heavy barrier below)
      int ug = (n0 >> 2) + eu;
      c1[(m0 + ebl) * 512 + ug] = creg0;
      c1[(m0 + ebl + 32) * 512 + ug] = creg1;
    }
  }
  gbar_acq(g, sub);   // phase edge: flush eo + c1, invalidate stale L2

  // ====== enc_proj = enc_out @ attn_W^T (f16), group-local rows ======
  for (int j = 0; j < 64; j++) {
    const int jj = r * 64 + j;
    const int ml = jj >> 3;
    const int nt = jj & 7;
    const int row0 = (g << 15) + ml * 64;
    f32x16 acc[2][2] = {{zv, zv}, {zv, zv}};
    gemm_ks<4, 0, 0>(Seg{eo, 512, row0}, Seg{eo, 512, row0}, 4,
                     wP1 + (size_t)nt * (4 * 8192), lane, wid, asg, acc);
    reduce8(acc, red, lane, wid);
    {
      int row = tid >> 3, col = (tid & 7) * 8;
      float4 a0 = rsum4(red, row, col);
      float4 a1 = rsum4(red, row, col + 4);
      f16x8 h8;
      h8[0] = (half_t)a0.x; h8[1] = (half_t)a0.y; h8[2] = (half_t)a0.z; h8[3] = (half_t)a0.w;
      h8[4] = (half_t)a1.x; h8[5] = (half_t)a1.y; h8[6] = (half_t)a1.z; h8[7] = (half_t)a1.w;
      *(f16x8*)&ep[(size_t)(row0 + row) * 512 + nt * 64 + col] = h8;  // plain
    }
    __syncthreads();
  }
  gbar_acq(g, sub);   // phase edge: flush ep

  // ================= decoder: 30 steps (d=30 = final output-only pass) ======
  for (int d = 0; d <= 30; d++) {
    const half_t* hs = (d == 0) ? (h1bB + 256 * 512) : hd1;

    // ---- P1: h1 @ [attn_W | dWhh0 | out_W]: tiles 0..39 + 72, 1 GEMM/block --
    {
      const int jj = (r < 40) ? r : ((r == 63) ? 72 : -1);
      if (jj >= 0) {
        const int n0p = jj * 64;
        f32x16 acc[2][2] = {{zv, zv}, {zv, zv}};
        gemm_ks<4, AUXC, AUXC>(Seg{hs, 512, m0}, Seg{hs, 512, m0}, 4,
                               wP1 + (size_t)jj * (4 * 8192), lane, wid, asg, acc);
        reduce8(acc, red, lane, wid);
        if (n0p < 4608) {
          #pragma unroll
          for (int it = 0; it < 2; it++) {
            int q = it * 512 + tid;
            int row = q >> 4, col = (q & 15) * 4;
            float4 v4 = rsum4(red, row, col);
            float* dst = &gates[(size_t)(m0 + row) * 4672 + n0p + col];
            st64(dst, v4.x, v4.y);
            st64(dst + 2, v4.z, v4.w);
          }
        } else if (d > 0) {
          if (tid < 64) {
            int bg = m0 + tid;
            float v0 = red[8192 + tid * 64 + 0] + red[12288 + tid * 64 + 0] + out_b[0];
            float v1 = red[8192 + tid * 64 + 1] + red[12288 + tid * 64 + 1] + out_b[1];
            float v2 = red[8192 + tid * 64 + 2] + red[12288 + tid * 64 + 2] + out_b[2];
            out[(size_t)bg * 90 + (d - 1) * 3 + 0] = v0;
            out[(size_t)bg * 90 + (d - 1) * 3 + 1] = v1;
            out[(size_t)bg * 90 + (d - 1) * 3 + 2] = v2;
            stfa(&inp[bg], v1);
          }
        }
      }
    }
    gbarf(g, r, ++bstep);
    if (d == 30) break;

    // ---- P2: attention for batch row b = m0 + r ----
    {
      const int b = m0 + r;
      float* dpb = red;          // 512
      float* vb  = red + 512;    // 512
      float* eb  = red + 1024;   // 512
      float* ab2 = red + 2048;   // 512
      float* sc  = red + 2560;   // 16
      float* pm  = red + 4096;   // 8x512 ctx partials
      dpb[tid] = ldfa(&gates[(size_t)b * 4672 + tid]);
      vb[tid]  = attn_v[tid];
      __syncthreads();
      // hoist tt-invariant LDS reads into registers (were 16-way conflicted)
      float va[8], da[8];
      {
        float4 t0 = *(const float4*)&vb[lane * 8];
        float4 t1 = *(const float4*)&vb[lane * 8 + 4];
        float4 t2 = *(const float4*)&dpb[lane * 8];
        float4 t3 = *(const float4*)&dpb[lane * 8 + 4];
        va[0]=t0.x; va[1]=t0.y; va[2]=t0.z; va[3]=t0.w;
        va[4]=t1.x; va[5]=t1.y; va[6]=t1.z; va[7]=t1.w;
        da[0]=t2.x; da[1]=t2.y; da[2]=t2.z; da[3]=t2.w;
        da[4]=t3.x; da[5]=t3.y; da[6]=t3.z; da[7]=t3.w;
      }
      const half_t* eprow = ep + ((size_t)b << 18) + (size_t)(wid * 64) * 512 + lane * 8;
      for (int tt = 0; tt < 64; tt++) {
        f16x8 e8 = *(const f16x8*)(eprow + (size_t)tt * 512);
        float sum = 0.f;
        #pragma unroll
        for (int jq = 0; jq < 8; jq++)
          sum += va[jq] * ftanh((float)e8[jq] + da[jq]);
        #pragma unroll
        for (int off = 32; off > 0; off >>= 1) sum += __shfl_down(sum, off, 64);
        if (lane == 0) eb[wid * 64 + tt] = sum;
      }
      __syncthreads();
      float e0 = eb[tid];
      float mx = e0;
      #pragma unroll
      for (int off = 32; off > 0; off >>= 1) mx = fmaxf(mx, __shfl_xor(mx, off, 64));
      if (lane == 0) sc[wid] = mx;
      __syncthreads();
      mx = sc[0];
      #pragma unroll
      for (int q = 1; q < 8; q++) mx = fmaxf(mx, sc[q]);
      float x0 = __expf(e0 - mx);
      float ssum = x0;
      #pragma unroll
      for (int off = 32; off > 0; off >>= 1) ssum += __shfl_xor(ssum, off, 64);
      __syncthreads();
      if (lane == 0) sc[8 + wid] = ssum;
      __syncthreads();
      float tot = sc[8];
      #pragma unroll
      for (int q = 1; q < 8; q++) tot += sc[8 + q];
      float inv = 1.f / tot;
      ab2[tid] = x0 * inv;
      __syncthreads();
      float pacc[8] = {0,0,0,0,0,0,0,0};
      const half_t* eow = eo + ((size_t)b << 18) + (size_t)(wid * 64) * 512 + lane * 8;
      for (int tt = 0; tt < 64; tt++) {
        f16x8 h8 = *(const f16x8*)(eow + (size_t)tt * 512);
        float at = ab2[wid * 64 + tt];
        #pragma unroll
        for (int jq = 0; jq < 8; jq++) pacc[jq] += at * (float)h8[jq];
      }
      #pragma unroll
      for (int jq = 0; jq < 8; jq++) pm[wid * 512 + lane * 8 + jq] = pacc[jq];
      __syncthreads();
      float sctx = 0.f;
      #pragma unroll
      for (int w = 0; w < 8; w++) sctx += pm[w * 512 + tid];
      stha(&ctx[(b << 9) + tid], sctx);                          // coherent
    }
    gbarf(g, r, ++bstep);

    // ---- P3: r<32: gates0 = ctx @ dWih0[:,1:] + inp*w0col + partial -> h0d
    //          r>=32: dWhh1 partial tiles 40..71 (moved from P1; hs stable) ---
    if (r < 32) {
      const int n0 = r << 6;
      f32x16 acc[2][2] = {{zv, zv}, {zv, zv}};
      gemm_ks<4, AUXC, AUXC>(Seg{ctx, 512, m0}, Seg{ctx, 512, m0}, 4,
                             wD0 + (size_t)(n0 >> 6) * (4 * 8192), lane, wid, asg, acc);
      reduce8(acc, red, lane, wid);
      const float* bD0 = WSCF(O_BD0);
      const float* w0c = WSCF(O_W0C);
      #pragma unroll
      for (int it = 0; it < 2; it++) {
        int q = it * 512 + tid;
        int u = q & 15, bl = q >> 4;
        int bg = m0 + bl, ug = (n0 >> 2) + u, nl = n0 + u * 4;
        float4 g4 = rsum4(red, bl, u * 4);
        float p0, p1, p2, p3;
        ld64(&gates[(size_t)bg * 4672 + 512 + nl], p0, p1);
        ld64(&gates[(size_t)bg * 4672 + 512 + nl + 2], p2, p3);
        float4 b4 = *(const float4*)&bD0[nl];
        float4 w4 = *(const float4*)&w0c[nl];
        float iv = ldfa(&inp[bg]);
        float gi = g4.x + p0 + b4.x + iv * w4.x;
        float gf = g4.y + p1 + b4.y + iv * w4.y;
        float gz = g4.z + p2 + b4.z + iv * w4.z;
        float go = g4.w + p3 + b4.w + iv * w4.w;
        float cold = c1[bg * 512 + ug];
        float cn = fsig(gf) * cold + fsig(gi) * ftanh(gz);
        stha(&h0d[bg * 512 + ug], fsig(go) * ftanh(cn));        // coherent
      }
    } else {
      const int jj = 8 + r;                 // r=32..63 -> tiles 40..71
      const int n0p = jj * 64;
      f32x16 acc[2][2] = {{zv, zv}, {zv, zv}};
      gemm_ks<4, AUXC, AUXC>(Seg{hs, 512, m0}, Seg{hs, 512, m0}, 4,
                             wP1 + (size_t)jj * (4 * 8192), lane, wid, asg, acc);
      reduce8(acc, red, lane, wid);
      #pragma unroll
      for (int it = 0; it < 2; it++) {
        int q = it * 512 + tid;
        int row = q >> 4, col = (q & 15) * 4;
        float4 v4 = rsum4(red, row, col);
        float* dst = &gates[(size_t)(m0 + row) * 4672 + n0p + col];
        st64(dst, v4.x, v4.y);
        st64(dst + 2, v4.z, v4.w);
      }
    }
    gbarf(g, r, ++bstep);

    // ---- P4: gates1 = h0d @ dWih1 + partial + bias -> c1, hd1 ----
    if (r < 32) {
      const int n0 = r << 6;
      f32x16 acc[2][2] = {{zv, zv}, {zv, zv}};
      gemm_ks<4, AUXC, AUXC>(Seg{h0d, 512, m0}, Seg{h0d, 512, m0}, 4,
                             wD1 + (size_t)(n0 >> 6) * (4 * 8192), lane, wid, asg, acc);
      reduce8(acc, red, lane, wid);
      const float* bD1 = WSCF(O_BD1);
      #pragma unroll
      for (int it = 0; it < 2; it++) {
        int q = it * 512 + tid;
        int u = q & 15, bl = q >> 4;
        int bg = m0 + bl, ug = (n0 >> 2) + u, nl = n0 + u * 4;
        float4 g4 = rsum4(red, bl, u * 4);
        float p0, p1, p2, p3;
        ld64(&gates[(size_t)bg * 4672 + 2560 + nl], p0, p1);
        ld64(&gates[(size_t)bg * 4672 + 2560 + nl + 2], p2, p3);
        float4 b4 = *(const float4*)&bD1[nl];
        float gi = g4.x + p0 + b4.x;
        float gf = g4.y + p1 + b4.y;
        float gz = g4.z + p2 + b4.z;
        float go = g4.w + p3 + b4.w;
        float cold = c1[bg * 512 + ug];
        float cn = fsig(gf) * cold + fsig(gi) * ftanh(gz);
        float hn = fsig(go) * ftanh(cn);
        c1[bg * 512 + ug] = cn;                                  // self-read only
        stha(&hd1[bg * 512 + ug], hn);                           // coherent
      }
    }
    gbarf(g, r, ++bstep);
  }
}

// ---------------- prep kernels ----------------
__global__ void kpackB(size_t dstOff, int id, int Ntiles, int NC,
                       const float* s0, const float* s1,
                       const float* s2, const float* s3) {
  half_t* dst = (half_t*)(g_ws + dstOff);
  size_t total = (size_t)Ntiles * NC * 8192;
  size_t i = (size_t)blockIdx.x * 256 + threadIdx.x;
  size_t stride = (size_t)gridDim.x * 256;
  for (size_t e = i; e < total; e += stride) {
    int j = e & 7;
    int l = (e >> 3) & 63;
    int bh = (e >> 9) & 1;
    int w = (e >> 10) & 7;
    int tc = (int)(e >> 13);
    int c = tc % NC;
    int tile = tc / NC;
    int n = tile * 64 + bh * 32 + (l & 31);
    int k = c * 128 + w * 16 + ((l >> 5) << 3) + j;
    float v = 0.f;
    if (id == 0) {          // wL0: [Wih0(64) | pad(64) | Whh0(512)]
      int pn = gperm(n);
      if (k < 64) v = s0[(size_t)pn * 64 + k];
      else if (k >= 128) v = s1[(size_t)pn * 512 + (k - 128)];
    } else if (id == 1) {   // wL1: [Wih1(512) | Whh1(512)]
      int pn = gperm(n);
      v = (k < 512) ? s0[(size_t)pn * 512 + k] : s1[(size_t)pn * 512 + (k - 512)];
    } else if (id == 2) {   // wP1: [attnW | dWhh0 | dWhh1 | outW | pad]
      if (n < 512) v = s0[((size_t)n << 9) + k];
      else if (n < 2560) v = s1[((size_t)gperm(n - 512) << 9) + k];
      else if (n < 4608) v = s2[((size_t)gperm(n - 2560) << 9) + k];
      else if (n < 4611) v = s3[((size_t)(n - 4608) << 9) + k];
    } else if (id == 3) {   // wD0: dec_Wih0[:,1:]
      v = s0[(size_t)gperm(n) * 513 + 1 + k];
    } else {                // wD1
      v = s0[((size_t)gperm(n) << 9) + k];
    }
    dst[e] = (half_t)v;
  }
}

__global__ void kmisc(const float* ebih0, const float* ebhh0, const float* ebih1, const float* ebhh1,
                      const float* dbih0, const float* dbhh0, const float* dbih1, const float* dbhh1,
                      const float* dWih0, const float* x) {
  float* bL0 = WSF(O_BL0);
  float* bL1 = WSF(O_BL1);
  float* bD0 = WSF(O_BD0);
  float* bD1 = WSF(O_BD1);
  float* w0c = WSF(O_W0C);
  half_t* h0b = WSH(O_H0B);
  half_t* h1b = WSH(O_H1B);
  float* c1 = WSF(O_C1);
  float* inp = WSF(O_INP);
  int i = blockIdx.x * 256 + threadIdx.x, stride = gridDim.x * 256;
  for (int idx = i; idx < 262144; idx += stride) {
    if (idx < 2048) {
      int pn = gperm(idx);
      bL0[idx] = ebih0[pn] + ebhh0[pn];
      bL1[idx] = ebih1[pn] + ebhh1[pn];
      bD0[idx] = dbih0[pn] + dbhh0[pn];
      bD1[idx] = dbih1[pn] + dbhh1[pn];
      w0c[idx] = dWih0[(size_t)pn * 513];
      g_bar[idx] = 0;
    }
    if (idx < 1024) g_flags[idx] = 0;
    if (idx < 256) inp[idx] = x[((size_t)idx * 512 + 511) * 64];
    h0b[idx] = (half_t)0.f;
    h1b[idx] = (half_t)0.f;
    if (idx < 131072) c1[idx] = 0.f;
  }
}

__global__ void kx16(const float* x) {
  half_t* dst = WSH(O_X16);   // (t, b, 128) zero-padded cols 64..127
  size_t i = (size_t)blockIdx.x * 256 + threadIdx.x;
  size_t stride = (size_t)gridDim.x * 256;
  for (size_t e = i; e < (size_t)512 * 256 * 128; e += stride) {
    int t = (int)(e >> 15);
    int b = (int)((e >> 7) & 255);
    int ii = (int)(e & 127);
    dst[e] = (ii < 64) ? (half_t)x[((size_t)b * 512 + t) * 64 + ii] : (half_t)0.f;
  }
}

// ---------------- launch ----------------
extern "C" void kernel_launch(void* const* d_in, const int* in_sizes, int n_in,
                              void* d_out, int out_size, void* d_ws, size_t ws_size,
                              hipStream_t stream) {
  const float* x     = (const float*)d_in[0];
  const float* eWih0 = (const float*)d_in[1];
  const float* eWhh0 = (const float*)d_in[2];
  const float* ebih0 = (const float*)d_in[3];
  const float* ebhh0 = (const float*)d_in[4];
  const float* eWih1 = (const float*)d_in[5];
  const float* eWhh1 = (const float*)d_in[6];
  const float* ebih1 = (const float*)d_in[7];
  const float* ebhh1 = (const float*)d_in[8];
  const float* dWih0 = (const float*)d_in[9];
  const float* dWhh0 = (const float*)d_in[10];
  const float* dbih0 = (const float*)d_in[11];
  const float* dbhh0 = (const float*)d_in[12];
  const float* dWih1 = (const float*)d_in[13];
  const float* dWhh1 = (const float*)d_in[14];
  const float* dbih1 = (const float*)d_in[15];
  const float* dbhh1 = (const float*)d_in[16];
  const float* attnW = (const float*)d_in[17];
  const float* attnv = (const float*)d_in[18];
  const float* outW  = (const float*)d_in[19];
  const float* outb  = (const float*)d_in[20];
  (void)in_sizes; (void)n_in; (void)out_size; (void)d_ws; (void)ws_size;

  kpackB<<<1024, 256, 0, stream>>>(O_WL0, 0, 32, 5, eWih0, eWhh0, nullptr, nullptr);
  kpackB<<<1024, 256, 0, stream>>>(O_WL1, 1, 32, 8, eWih1, eWhh1, nullptr, nullptr);
  kpackB<<<1024, 256, 0, stream>>>(O_WP1, 2, 73, 4, attnW, dWhh0, dWhh1, outW);
  kpackB<<<1024, 256, 0, stream>>>(O_WD0, 3, 32, 4, dWih0, nullptr, nullptr, nullptr);
  kpackB<<<1024, 256, 0, stream>>>(O_WD1, 4, 32, 4, dWih1, nullptr, nullptr, nullptr);
  kmisc<<<1024, 256, 0, stream>>>(ebih0, ebhh0, ebih1, ebhh1,
                                  dbih0, dbhh0, dbih1, dbhh1, dWih0, x);
  kx16<<<2048, 256, 0, stream>>>(x);

  float* outp = (float*)d_out;
  void* args[] = {(void*)&attnv, (void*)&outb, (void*)&outp};
  hipError_t e = hipLaunchCooperativeKernel((void*)kmain, dim3(256), dim3(512),
                                            args, 0, stream);
  if (e != hipSuccess) {
    kmain<<<dim3(256), dim3(512), 0, stream>>>(attnv, outb, outp);
  }
}

// Round 4
// 6893.215 us; speedup vs baseline: 1.3072x; 1.2448x over previous
//
#include <hip/hip_runtime.h>

// ---------------------------------------------------------------------------
// Seq2Seq LSTM + attention, persistent kernel for MI355X (gfx950)
// B=256, T=512, I=64, H=512, HORIZON=30, NQ=3
// R11: de-risked R10. 8 groups x 32 blocks (group = blockIdx&7 -> one XCD
// under round-robin dispatch). Each block computes BOTH the L0 and L1 64-gate
// tile of its group's 32 batch rows (h0 staged once, shared by both layers).
// FAST mode: DATA traffic (h publishes/stages, gates, ctx) uses sc0 only
// (XCD-L2 coherent, ~200cy) -- but BARRIER FLAGS are ALWAYS agent-scope
// (sc0|sc1, R7-proven): a wrong FAST vote can only yield stale data (clean
// absmax failure), never a deadlock. Vote hardened: FAST requires group's 32
// XCC IDs uniform AND != neighbor group's ID (constant-garbage getreg fails
// the diversity check -> SLOW). SLOW mode = R7 agent-scope coherence.
// Carried: conflict-free 3-sync K-split reduction, flag-vote barrier, P2
// register-hoisted attention, encoder weights in VGPRs.
// ---------------------------------------------------------------------------

typedef _Float16 half_t;
typedef __attribute__((ext_vector_type(8)))  _Float16 f16x8;
typedef __attribute__((ext_vector_type(16))) float    f32x16;

#define MFMA(a,b,c) __builtin_amdgcn_mfma_f32_32x32x16_f16((a),(b),(c),0,0,0)
#define CBAR()      asm volatile("" ::: "memory")

template<int N> __device__ __forceinline__ void waitvm() {
  asm volatile("s_waitcnt vmcnt(%0)" :: "n"(N) : "memory");
}

__device__ __forceinline__ float fsig(float x)  { return 1.0f / (1.0f + __expf(-x)); }
__device__ __forceinline__ float ftanh(float x) { return 1.0f - 2.0f / (1.0f + __expf(2.0f * x)); }

union FU { float f; unsigned u; };
union HU { _Float16 h; unsigned short u; };

// ---------------- coherent scalar ops: FAST = sc0 (XCD L2), SLOW = agent ----
template<bool FAST>
__device__ __forceinline__ float ldfa(const float* p) {
  if constexpr (FAST) {
    float v;
    asm volatile("global_load_dword %0, %1, off sc0\n\ts_waitcnt vmcnt(0)"
                 : "=v"(v) : "v"(p) : "memory");
    return v;
  } else {
    unsigned v = __hip_atomic_load((const unsigned*)p, __ATOMIC_RELAXED, __HIP_MEMORY_SCOPE_AGENT);
    FU c; c.u = v; return c.f;
  }
}
template<bool FAST>
__device__ __forceinline__ void stfa(float* p, float v) {
  FU c; c.f = v;
  if constexpr (FAST)
    asm volatile("global_store_dword %0, %1, off sc0" :: "v"(p), "v"(c.u) : "memory");
  else
    __hip_atomic_store((unsigned*)p, c.u, __ATOMIC_RELAXED, __HIP_MEMORY_SCOPE_AGENT);
}
template<bool FAST>
__device__ __forceinline__ void stha(half_t* p, float v) {
  HU c; c.h = (half_t)v;
  if constexpr (FAST)
    asm volatile("global_store_short %0, %1, off sc0" :: "v"(p), "v"((unsigned)c.u) : "memory");
  else
    __hip_atomic_store((unsigned short*)p, c.u, __ATOMIC_RELAXED, __HIP_MEMORY_SCOPE_AGENT);
}
template<bool FAST>
__device__ __forceinline__ void st64(float* p, float a, float b) {
  FU x, y; x.f = a; y.f = b;
  unsigned long long v = (unsigned long long)x.u | ((unsigned long long)y.u << 32);
  if constexpr (FAST)
    asm volatile("global_store_dwordx2 %0, %1, off sc0" :: "v"(p), "v"(v) : "memory");
  else
    __hip_atomic_store((unsigned long long*)p, v, __ATOMIC_RELAXED, __HIP_MEMORY_SCOPE_AGENT);
}
template<bool FAST>
__device__ __forceinline__ void ld64(const float* p, float& a, float& b) {
  unsigned long long v;
  if constexpr (FAST) {
    asm volatile("global_load_dwordx2 %0, %1, off sc0\n\ts_waitcnt vmcnt(0)"
                 : "=v"(v) : "v"(p) : "memory");
  } else {
    v = __hip_atomic_load((const unsigned long long*)p, __ATOMIC_RELAXED, __HIP_MEMORY_SCOPE_AGENT);
  }
  FU x, y; x.u = (unsigned)v; y.u = (unsigned)(v >> 32); a = x.f; b = y.f;
}

// ---------------- workspace layout (bytes, inside g_ws) ----------------
static constexpr size_t O_X16 = 0;                             // (T,B,128) f16 x zero-padded
static constexpr size_t O_WL0 = O_X16 + (size_t)512*256*128*2; // 32t x 5c packed  (2048x640)
static constexpr size_t O_WL1 = O_WL0 + (size_t)2048*640*2;    // 32t x 8c packed  (2048x1024)
static constexpr size_t O_WP1 = O_WL1 + (size_t)2048*1024*2;   // 73t x 4c packed  (4672x512)
static constexpr size_t O_WD0 = O_WP1 + (size_t)4672*512*2;    // 32t x 4c packed
static constexpr size_t O_WD1 = O_WD0 + (size_t)2048*512*2;    // 32t x 4c packed
static constexpr size_t O_BL0 = O_WD1 + (size_t)2048*512*2;    // 2048 f32 biases (gate-permuted)
static constexpr size_t O_BL1 = O_BL0 + 8192;
static constexpr size_t O_BD0 = O_BL1 + 8192;
static constexpr size_t O_BD1 = O_BD0 + 8192;
static constexpr size_t O_W0C = O_BD1 + 8192;                  // 2048 f32 dec_Wih0[:,0] permuted
static constexpr size_t O_H0B = O_W0C + 8192;                  // 2 x (256,512) f16 L0 h ping-pong
static constexpr size_t O_H1B = O_H0B + (size_t)2*256*512*2;   // 2 x (256,512) f16 L1 h ping-pong
static constexpr size_t O_HD1 = O_H1B + (size_t)2*256*512*2;   // (256,512) f16 decoder h1
static constexpr size_t O_H0D = O_HD1 + (size_t)256*512*2;     // (256,512) f16 decoder h0
static constexpr size_t O_CTX = O_H0D + (size_t)256*512*2;     // (256,512) f16 context
static constexpr size_t O_C0  = O_CTX + (size_t)256*512*2;     // (256,512) f32 (unused scratch)
static constexpr size_t O_C1  = O_C0  + (size_t)256*512*4;     // (256,512) f32
static constexpr size_t O_INP = O_C1  + (size_t)256*512*4;     // 256 f32
static constexpr size_t O_GAT = O_INP + 1024;                  // (256,4672) f32 gate partials
static constexpr size_t O_EO  = O_GAT + (size_t)256*4672*4;    // (B*T,H) f16 encoder outputs
static constexpr size_t O_EP  = O_EO  + (size_t)256*512*512*2; // (B*T,512) f16 enc_proj
static constexpr size_t WS_NEED = O_EP + (size_t)256*512*512*2;

__device__ __align__(4096) unsigned char g_ws[WS_NEED];
__device__ int g_bar[2048];    // heavy-barrier lines
__device__ int g_flags[1024];  // 8 groups x 32 block flags (128B/group)
__device__ int g_xcc[256];     // per-block XCC id (+1)

#define WSH(o) ((half_t*)(g_ws + (o)))
#define WSCH(o) ((const half_t*)(g_ws + (o)))
#define WSF(o) ((float*)(g_ws + (o)))
#define WSCF(o) ((const float*)(g_ws + (o)))
#define BLINE(i) (g_bar + ((size_t)(i) << 5))

__device__ __forceinline__ int gperm(int n) { return (n & 3) * 512 + (n >> 2); }

// ------- flag-vote group barrier (32 blocks): ALWAYS agent-scope flags ------
// Deadlock-proof by construction: flags go through L3 regardless of mode, so
// a mistaken FAST vote can only produce stale *data* (detectable), not a hang.
__device__ __forceinline__ void gbarf(int g, int r, int step) {
  __syncthreads();   // drains vmcnt(0): all prior stores at their coherence pt
  if (threadIdx.x < 64) {
    if (threadIdx.x == 0)
      __hip_atomic_store(&g_flags[(g << 5) + r], step,
                         __ATOMIC_RELAXED, __HIP_MEMORY_SCOPE_AGENT);
    const int* fp = &g_flags[(g << 5) + (threadIdx.x & 31)];
    for (;;) {
      int v = __hip_atomic_load(fp, __ATOMIC_RELAXED, __HIP_MEMORY_SCOPE_AGENT);
      if (__all(v >= step)) break;
      __builtin_amdgcn_s_sleep(1);
    }
  }
  __syncthreads();
}

// Heavy barrier: full grid, release (L2 writeback) / acquire (L2 inv).
__device__ __forceinline__ void gbar_acq8() {
  __syncthreads();
  if (threadIdx.x == 0) {
    const int g = blockIdx.x & 7;
    int* cnt = BLINE(g);
    int* mst = BLINE(8);
    int* gs  = BLINE(16 + g);
    int old = __hip_atomic_load(gs, __ATOMIC_RELAXED, __HIP_MEMORY_SCOPE_AGENT);
    int a = __hip_atomic_fetch_add(cnt, 1, __ATOMIC_ACQ_REL, __HIP_MEMORY_SCOPE_AGENT);
    if (a == 31) {
      __hip_atomic_store(cnt, 0, __ATOMIC_RELAXED, __HIP_MEMORY_SCOPE_AGENT);
      int m = __hip_atomic_fetch_add(mst, 1, __ATOMIC_ACQ_REL, __HIP_MEMORY_SCOPE_AGENT);
      if (m == 7) {
        __hip_atomic_store(mst, 0, __ATOMIC_RELAXED, __HIP_MEMORY_SCOPE_AGENT);
        for (int q = 0; q < 8; q++)
          __hip_atomic_fetch_add(BLINE(16 + q), 1, __ATOMIC_RELEASE, __HIP_MEMORY_SCOPE_AGENT);
      }
    }
    while (__hip_atomic_load(gs, __ATOMIC_RELAXED, __HIP_MEMORY_SCOPE_AGENT) == old)
      __builtin_amdgcn_s_sleep(2);
    (void)__hip_atomic_load(gs, __ATOMIC_ACQUIRE, __HIP_MEMORY_SCOPE_AGENT);
  }
  __syncthreads();
}

// ---------------- async global->LDS helper ----------------
template<int AX>
__device__ __forceinline__ void gld(const half_t* gp, char* lp) {
  __builtin_amdgcn_global_load_lds(
      (const __attribute__((address_space(1))) unsigned int*)gp,
      (__attribute__((address_space(3))) unsigned int*)lp, 16, 0, AX);
}

// ---------------- 64-row GEMM core (enc_proj only), as in R7 ----------------
struct Seg { const half_t* p; int stride; int row0; };

template<int AXA, int AXB>
__device__ __forceinline__ void stageA(Seg sa, Seg sb, int cSplit, int c,
                                       int lane, int wid, char* dst) {
  bool isA = c < cSplit;
  Seg s = isA ? sa : sb;
  int kb = (isA ? c : (c - cSplit)) * 128;
  const half_t* gp = s.p + (size_t)(s.row0 + (lane & 31)) * s.stride
                         + kb + (wid << 4) + ((lane >> 5) << 3);
  if (isA) {
    gld<AXA>(gp, dst);
    gld<AXA>(gp + (size_t)32 * s.stride, dst + 1024);
  } else {
    gld<AXB>(gp, dst);
    gld<AXB>(gp + (size_t)32 * s.stride, dst + 1024);
  }
}

template<int C, int NC>
__device__ __forceinline__ void kks(int lane, int wid, char* asg, f32x16 acc[2][2],
                                    f16x8 (&b0)[4], f16x8 (&b1)[4]) {
  if constexpr (C < NC) {
    waitvm<4 * (NC - 1 - C)>();
    char* ab = asg + (size_t)(C * 8 + wid) * 2048 + lane * 16;
    f16x8 a0 = *(const f16x8*)ab;
    f16x8 a1 = *(const f16x8*)(ab + 1024);
    acc[0][0] = MFMA(a0, b0[C], acc[0][0]);
    acc[0][1] = MFMA(a0, b1[C], acc[0][1]);
    acc[1][0] = MFMA(a1, b0[C], acc[1][0]);
    acc[1][1] = MFMA(a1, b1[C], acc[1][1]);
    CBAR();
    kks<C + 1, NC>(lane, wid, asg, acc, b0, b1);
  }
}

template<int NC, int AXA, int AXB>
__device__ __forceinline__ void gemm_ks(Seg sa, Seg sb, int cSplit, const half_t* Wt,
                                        int lane, int wid, char* asg, f32x16 acc[2][2]) {
  const half_t* wb = Wt + (wid << 1) * 512 + lane * 8;
  f16x8 b0[4], b1[4];
  #pragma unroll
  for (int c = 0; c < NC; c++) {
    stageA<AXA, AXB>(sa, sb, cSplit, c, lane, wid, asg + (size_t)(c * 8 + wid) * 2048);
    CBAR();
    b0[c] = *(const f16x8*)(wb + (size_t)c * 8192);
    b1[c] = *(const f16x8*)(wb + (size_t)c * 8192 + 512);
    CBAR();
  }
  kks<0, NC>(lane, wid, asg, acc, b0, b1);
}

// ---------------- 32-row GEMM core (decoder phases) ----------------
// vm op order per chunk pinned by CBAR: [gld, b0, b1] -> gld_c is op 3c+1.
template<int C, int NC>
__device__ __forceinline__ void kks32(char* wslr, f32x16 (&acc)[2][2],
                                      f16x8 (&b0)[4], f16x8 (&b1)[4]) {
  if constexpr (C < NC) {
    waitvm<3 * (NC - 1 - C) + 2>();
    f16x8 a = *(const f16x8*)(wslr + C * 8192);
    acc[0][0] = MFMA(a, b0[C], acc[0][0]);
    acc[0][1] = MFMA(a, b1[C], acc[0][1]);
    CBAR();
    kks32<C + 1, NC>(wslr, acc, b0, b1);
  }
}

template<int NC, int AX>
__device__ __forceinline__ void gemm_ks32(const half_t* aP, const half_t* Wt,
                                          int lane, int wid, char* asg, f32x16 (&acc)[2][2]) {
  char* wsl = asg + wid * 1024;
  const half_t* wb = Wt + (wid << 1) * 512 + lane * 8;
  f16x8 b0[4], b1[4];
  #pragma unroll
  for (int c = 0; c < NC; c++) {
    gld<AX>(aP + c * 128, wsl + c * 8192);
    CBAR();
    b0[c] = *(const f16x8*)(wb + (size_t)c * 8192);
    b1[c] = *(const f16x8*)(wb + (size_t)c * 8192 + 512);
    CBAR();
  }
  kks32<0, NC>(wsl + lane * 16, acc, b0, b1);
}

// ---------------- encoder K-bodies: 9 staged slots, weights in VGPRs --------
template<int C>
__device__ __forceinline__ void encL0(const char* wslr, const f16x8 (&B0)[5],
                                      const f16x8 (&B1)[5], f32x16 (&acc)[2][2]) {
  if constexpr (C < 5) {
    waitvm<8 - C>();
    f16x8 a = *(const f16x8*)(wslr + C * 8192);
    acc[0][0] = MFMA(a, B0[C], acc[0][0]);
    acc[0][1] = MFMA(a, B1[C], acc[0][1]);
    CBAR();
    encL0<C + 1>(wslr, B0, B1, acc);
  }
}
template<int C>
__device__ __forceinline__ void encL1(const char* wslr, const f16x8 (&B0)[8],
                                      const f16x8 (&B1)[8], f32x16 (&acc)[2][2]) {
  if constexpr (C < 8) {
    if constexpr (C >= 4) waitvm<7 - C>();
    f16x8 a = *(const f16x8*)(wslr + (C + 1) * 8192);
    acc[1][0] = MFMA(a, B0[C], acc[1][0]);
    acc[1][1] = MFMA(a, B1[C], acc[1][1]);
    CBAR();
    encL1<C + 1>(wslr, B0, B1, acc);
  }
}

// ---------------- K-split reduction: 3 syncs, conflict-free -----------------
__device__ __forceinline__ void acc_wr(float* dst, int lane, f32x16 acc[2][2]) {
  #pragma unroll
  for (int t = 0; t < 4; t++) {
    f32x16 a = acc[t >> 1][t & 1];
    #pragma unroll
    for (int r4 = 0; r4 < 4; r4++)
      *(float4*)(dst + ((t * 4 + r4) * 64 + lane) * 4) =
          make_float4(a[r4*4], a[r4*4+1], a[r4*4+2], a[r4*4+3]);
  }
}
__device__ __forceinline__ void acc_add(const float* src, int lane, f32x16 acc[2][2]) {
  #pragma unroll
  for (int t = 0; t < 4; t++) {
    #pragma unroll
    for (int r4 = 0; r4 < 4; r4++) {
      float4 v = *(const float4*)(src + ((t * 4 + r4) * 64 + lane) * 4);
      acc[t>>1][t&1][r4*4]   += v.x;
      acc[t>>1][t&1][r4*4+1] += v.y;
      acc[t>>1][t&1][r4*4+2] += v.z;
      acc[t>>1][t&1][r4*4+3] += v.w;
    }
  }
}
__device__ __forceinline__ void reduce8(f32x16 acc[2][2], float* red, int lane, int wid) {
  if (wid >= 4) acc_wr(red + (size_t)(wid - 4) * 4096, lane, acc);
  __syncthreads();
  if (wid < 4) acc_add(red + (size_t)wid * 4096, lane, acc);
  if (wid == 2 || wid == 3) acc_wr(red + (size_t)wid * 4096, lane, acc);
  __syncthreads();
  if (wid < 2) {
    acc_add(red + (size_t)(wid + 2) * 4096, lane, acc);
    float* zone = red + 8192 + (size_t)wid * 4096;
    #pragma unroll
    for (int ms = 0; ms < 2; ms++)
      #pragma unroll
      for (int ns = 0; ns < 2; ns++)
        #pragma unroll
        for (int rr = 0; rr < 16; rr++) {
          int row = ms * 32 + (rr & 3) + ((rr >> 2) << 3) + ((lane >> 5) << 2);
          zone[row * 64 + ns * 32 + (lane & 31)] = acc[ms][ns][rr];
        }
  }
  __syncthreads();
}
__device__ __forceinline__ float4 rsum4(const float* red, int row, int col) {
  float4 a = *(const float4*)&red[8192 + row * 64 + col];
  float4 b = *(const float4*)&red[12288 + row * 64 + col];
  return make_float4(a.x + b.x, a.y + b.y, a.z + b.z, a.w + b.w);
}

// ---------------- main body, templated on coherence mode ----------------
template<bool FAST>
__device__ __noinline__ void run_all(int g, int r, const float* attn_v,
                                     const float* out_b, float* out,
                                     char* asg, float* red) {
  constexpr int AXH = FAST ? 1 : 17;          // sc0 (XCD L2) vs sc0|sc1 (agent)
  constexpr size_t PP = (size_t)256 * 512;

  const half_t* x16 = WSCH(O_X16);
  const half_t* wL0 = WSCH(O_WL0);
  const half_t* wL1 = WSCH(O_WL1);
  const half_t* wP1 = WSCH(O_WP1);
  const half_t* wD0 = WSCH(O_WD0);
  const half_t* wD1 = WSCH(O_WD1);
  half_t* h0bB = WSH(O_H0B);
  half_t* h1bB = WSH(O_H1B);
  half_t* hd1  = WSH(O_HD1);
  half_t* h0d  = WSH(O_H0D);
  half_t* ctx  = WSH(O_CTX);
  half_t* eo   = WSH(O_EO);
  half_t* ep   = WSH(O_EP);
  float* c1 = WSF(O_C1);
  float* inp = WSF(O_INP);
  float* gates = WSF(O_GAT);

  const int tid = threadIdx.x;
  const int wid = tid >> 6;
  const int lane = tid & 63;
  const int m0 = g << 5;                      // 32 batch rows per group
  const f32x16 zv = {0,0,0,0,0,0,0,0,0,0,0,0,0,0,0,0};
  int bstep = 0;

  const int koff = (wid << 4) + ((lane >> 5) << 3);
  const size_t aofs = (size_t)(m0 + (lane & 31)) * 512 + koff;  // stride-512 A offset
  const size_t xofs = (size_t)(m0 + (lane & 31)) * 128 + koff;
  char* wsl = asg + wid * 1024;               // wave-uniform LDS slot base
  const char* wslr = wsl + lane * 16;         // per-lane LDS read base

  // ================= encoder: 513 steps, both layers per block ==============
  {
    const int n0 = r << 6;
    const half_t* wb0 = wL0 + (size_t)r * (5 * 8192) + (wid << 1) * 512 + lane * 8;
    const half_t* wb1 = wL1 + (size_t)r * (8 * 8192) + (wid << 1) * 512 + lane * 8;
    f16x8 B0L0[5], B1L0[5], B0L1[8], B1L1[8];
    #pragma unroll
    for (int c = 0; c < 5; c++) {
      B0L0[c] = *(const f16x8*)(wb0 + (size_t)c * 8192);
      B1L0[c] = *(const f16x8*)(wb0 + (size_t)c * 8192 + 512);
    }
    #pragma unroll
    for (int c = 0; c < 8; c++) {
      B0L1[c] = *(const f16x8*)(wb1 + (size_t)c * 8192);
      B1L1[c] = *(const f16x8*)(wb1 + (size_t)c * 8192 + 512);
    }
    const int eu = tid & 15, ebl = tid >> 4;
    const float4 breg0 = *(const float4*)&(WSCF(O_BL0))[n0 + eu * 4];
    const float4 breg1 = *(const float4*)&(WSCF(O_BL1))[n0 + eu * 4];
    const int bg = m0 + ebl, ug = (r << 4) + eu;
    float creg0 = 0.f, creg1 = 0.f;

    for (int s = 0; s <= 512; s++) {
      {  // stage 9 chunks: x(slot0), h0(1..4), h1(5..8); wave-private slots
        const int tc = s < 512 ? s : 511;
        const half_t* xp  = x16 + (((size_t)tc) << 15) + xofs;
        const half_t* h0p = h0bB + (size_t)((s + 1) & 1) * PP + aofs;
        const half_t* h1p = h1bB + (size_t)(s & 1) * PP + aofs;
        gld<0>(xp, wsl);
        #pragma unroll
        for (int c = 0; c < 4; c++) gld<AXH>(h0p + c * 128, wsl + (c + 1) * 8192);
        #pragma unroll
        for (int c = 0; c < 4; c++) gld<AXH>(h1p + c * 128, wsl + (c + 5) * 8192);
        CBAR();
      }
      f32x16 acc[2][2] = {{zv, zv}, {zv, zv}};
      encL0<0>(wslr, B0L0, B1L0, acc);        // acc[0] = L0 gates (rows 0..31)
      encL1<0>(wslr, B0L1, B1L1, acc);        // acc[1] = L1 gates (rows 0..31)
      reduce8(acc, red, lane, wid);
      if (s < 512) {                          // L0 epilogue (zone rows 0..31)
        float4 g4 = rsum4(red, ebl, eu * 4);
        float cn = fsig(g4.y + breg0.y) * creg0 + fsig(g4.x + breg0.x) * ftanh(g4.z + breg0.z);
        float hn = fsig(g4.w + breg0.w) * ftanh(cn);
        creg0 = cn;
        stha<FAST>(&h0bB[(size_t)(s & 1) * PP + (size_t)bg * 512 + ug], hn);
      }
      if (s > 0) {                            // L1 epilogue (zone rows 32..63)
        float4 g4 = rsum4(red, ebl + 32, eu * 4);
        float cn = fsig(g4.y + breg1.y) * creg1 + fsig(g4.x + breg1.x) * ftanh(g4.z + breg1.z);
        float hn = fsig(g4.w + breg1.w) * ftanh(cn);
        creg1 = cn;
        stha<FAST>(&h1bB[(size_t)((s + 1) & 1) * PP + (size_t)bg * 512 + ug], hn);
        eo[((size_t)bg * 512 + (s - 1)) * 512 + ug] = (half_t)hn;  // plain
      }
      gbarf(g, r, ++bstep);
    }
    c1[(size_t)bg * 512 + ug] = creg1;        // plain; flushed by heavy barrier
  }
  gbar_acq8();   // phase edge: flush eo + c1

  // ====== enc_proj = enc_out @ attn_W^T (f16), 64-row tiles ======
  for (int j = 0; j < 64; j++) {
    const int jj = (r << 6) + j;              // 0..2047
    const int ml = jj >> 3;
    const int nt = jj & 7;
    const int row0 = (g << 14) + ml * 64;
    f32x16 acc[2][2] = {{zv, zv}, {zv, zv}};
    gemm_ks<4, 0, 0>(Seg{eo, 512, row0}, Seg{eo, 512, row0}, 4,
                     wP1 + (size_t)nt * (4 * 8192), lane, wid, asg, acc);
    reduce8(acc, red, lane, wid);
    {
      int row = tid >> 3, col = (tid & 7) * 8;
      float4 a0 = rsum4(red, row, col);
      float4 a1 = rsum4(red, row, col + 4);
      f16x8 h8;
      h8[0] = (half_t)a0.x; h8[1] = (half_t)a0.y; h8[2] = (half_t)a0.z; h8[3] = (half_t)a0.w;
      h8[4] = (half_t)a1.x; h8[5] = (half_t)a1.y; h8[6] = (half_t)a1.z; h8[7] = (half_t)a1.w;
      *(f16x8*)&ep[(size_t)(row0 + row) * 512 + nt * 64 + col] = h8;  // plain
    }
    __syncthreads();
  }
  gbar_acq8();   // phase edge: flush ep

  // ================= decoder: 30 steps (d=30 = output-only pass) ============
  for (int d = 0; d <= 30; d++) {
    const half_t* hs = (d == 0) ? (h1bB + PP) : hd1;

    // ---- P1: h1 @ [attn_W | dWhh0 | dWhh1 | out_W], 73 tiles / 32 blocks ----
    for (int jj = r; jj < 73; jj += 32) {
      if (d == 30 && jj != 72) continue;
      f32x16 acc[2][2] = {{zv, zv}, {zv, zv}};
      gemm_ks32<4, AXH>(hs + aofs, wP1 + (size_t)jj * (4 * 8192), lane, wid, asg, acc);
      reduce8(acc, red, lane, wid);
      if (jj < 72) {
        int row = tid >> 4, col = (tid & 15) * 4;
        float4 v4 = rsum4(red, row, col);
        float* dst = &gates[(size_t)(m0 + row) * 4672 + jj * 64 + col];
        st64<FAST>(dst, v4.x, v4.y);
        st64<FAST>(dst + 2, v4.z, v4.w);
      } else if (d > 0) {
        if (tid < 32) {
          int bg = m0 + tid;
          float v0 = red[8192 + tid * 64 + 0] + red[12288 + tid * 64 + 0] + out_b[0];
          float v1 = red[8192 + tid * 64 + 1] + red[12288 + tid * 64 + 1] + out_b[1];
          float v2 = red[8192 + tid * 64 + 2] + red[12288 + tid * 64 + 2] + out_b[2];
          out[(size_t)bg * 90 + (d - 1) * 3 + 0] = v0;
          out[(size_t)bg * 90 + (d - 1) * 3 + 1] = v1;
          out[(size_t)bg * 90 + (d - 1) * 3 + 2] = v2;
          stfa<FAST>(&inp[bg], v1);
        }
      }
      __syncthreads();
    }
    gbarf(g, r, ++bstep);
    if (d == 30) break;

    // ---- P2: attention for batch row b = m0 + r ----
    {
      const int b = m0 + r;
      float* dpb = red;          // 512
      float* vb  = red + 512;    // 512
      float* eb  = red + 1024;   // 512
      float* ab2 = red + 2048;   // 512
      float* sc  = red + 2560;   // 16
      float* pm  = red + 4096;   // 8x512 ctx partials
      dpb[tid] = ldfa<FAST>(&gates[(size_t)b * 4672 + tid]);
      vb[tid]  = attn_v[tid];
      __syncthreads();
      float va[8], da[8];
      {
        float4 t0 = *(const float4*)&vb[lane * 8];
        float4 t1 = *(const float4*)&vb[lane * 8 + 4];
        float4 t2 = *(const float4*)&dpb[lane * 8];
        float4 t3 = *(const float4*)&dpb[lane * 8 + 4];
        va[0]=t0.x; va[1]=t0.y; va[2]=t0.z; va[3]=t0.w;
        va[4]=t1.x; va[5]=t1.y; va[6]=t1.z; va[7]=t1.w;
        da[0]=t2.x; da[1]=t2.y; da[2]=t2.z; da[3]=t2.w;
        da[4]=t3.x; da[5]=t3.y; da[6]=t3.z; da[7]=t3.w;
      }
      const half_t* eprow = ep + ((size_t)b << 18) + (size_t)(wid * 64) * 512 + lane * 8;
      for (int tt = 0; tt < 64; tt++) {
        f16x8 e8 = *(const f16x8*)(eprow + (size_t)tt * 512);
        float sum = 0.f;
        #pragma unroll
        for (int jq = 0; jq < 8; jq++)
          sum += va[jq] * ftanh((float)e8[jq] + da[jq]);
        #pragma unroll
        for (int off = 32; off > 0; off >>= 1) sum += __shfl_down(sum, off, 64);
        if (lane == 0) eb[wid * 64 + tt] = sum;
      }
      __syncthreads();
      float e0 = eb[tid];
      float mx = e0;
      #pragma unroll
      for (int off = 32; off > 0; off >>= 1) mx = fmaxf(mx, __shfl_xor(mx, off, 64));
      if (lane == 0) sc[wid] = mx;
      __syncthreads();
      mx = sc[0];
      #pragma unroll
      for (int q = 1; q < 8; q++) mx = fmaxf(mx, sc[q]);
      float x0 = __expf(e0 - mx);
      float ssum = x0;
      #pragma unroll
      for (int off = 32; off > 0; off >>= 1) ssum += __shfl_xor(ssum, off, 64);
      __syncthreads();
      if (lane == 0) sc[8 + wid] = ssum;
      __syncthreads();
      float tot = sc[8];
      #pragma unroll
      for (int q = 1; q < 8; q++) tot += sc[8 + q];
      float inv = 1.f / tot;
      ab2[tid] = x0 * inv;
      __syncthreads();
      float pacc[8] = {0,0,0,0,0,0,0,0};
      const half_t* eow = eo + ((size_t)b << 18) + (size_t)(wid * 64) * 512 + lane * 8;
      for (int tt = 0; tt < 64; tt++) {
        f16x8 h8 = *(const f16x8*)(eow + (size_t)tt * 512);
        float at = ab2[wid * 64 + tt];
        #pragma unroll
        for (int jq = 0; jq < 8; jq++) pacc[jq] += at * (float)h8[jq];
      }
      #pragma unroll
      for (int jq = 0; jq < 8; jq++) pm[wid * 512 + lane * 8 + jq] = pacc[jq];
      __syncthreads();
      float sctx = 0.f;
      #pragma unroll
      for (int w = 0; w < 8; w++) sctx += pm[w * 512 + tid];
      stha<FAST>(&ctx[((size_t)b << 9) + tid], sctx);
    }
    gbarf(g, r, ++bstep);

    // ---- P3: gates0 = ctx @ dWih0[:,1:] + inp*w0col + partial -> h0d ----
    {
      f32x16 acc[2][2] = {{zv, zv}, {zv, zv}};
      gemm_ks32<4, AXH>(ctx + aofs, wD0 + (size_t)r * (4 * 8192), lane, wid, asg, acc);
      reduce8(acc, red, lane, wid);
      const float* bD0 = WSCF(O_BD0);
      const float* w0c = WSCF(O_W0C);
      int u = tid & 15, bl = tid >> 4;
      int bg = m0 + bl, ug = (r << 4) + u, nl = (r << 6) + u * 4;
      float4 g4 = rsum4(red, bl, u * 4);
      float p0, p1, p2, p3;
      ld64<FAST>(&gates[(size_t)bg * 4672 + 512 + nl], p0, p1);
      ld64<FAST>(&gates[(size_t)bg * 4672 + 512 + nl + 2], p2, p3);
      float4 b4 = *(const float4*)&bD0[nl];
      float4 w4 = *(const float4*)&w0c[nl];
      float iv = ldfa<FAST>(&inp[bg]);
      float gi = g4.x + p0 + b4.x + iv * w4.x;
      float gf = g4.y + p1 + b4.y + iv * w4.y;
      float gz = g4.z + p2 + b4.z + iv * w4.z;
      float go = g4.w + p3 + b4.w + iv * w4.w;
      float cold = c1[(size_t)bg * 512 + ug];
      float cn = fsig(gf) * cold + fsig(gi) * ftanh(gz);
      stha<FAST>(&h0d[(size_t)bg * 512 + ug], fsig(go) * ftanh(cn));
    }
    gbarf(g, r, ++bstep);

    // ---- P4: gates1 = h0d @ dWih1 + partial + bias -> c1, hd1 ----
    {
      f32x16 acc[2][2] = {{zv, zv}, {zv, zv}};
      gemm_ks32<4, AXH>(h0d + aofs, wD1 + (size_t)r * (4 * 8192), lane, wid, asg, acc);
      reduce8(acc, red, lane, wid);
      const float* bD1 = WSCF(O_BD1);
      int u = tid & 15, bl = tid >> 4;
      int bg = m0 + bl, ug = (r << 4) + u, nl = (r << 6) + u * 4;
      float4 g4 = rsum4(red, bl, u * 4);
      float p0, p1, p2, p3;
      ld64<FAST>(&gates[(size_t)bg * 4672 + 2560 + nl], p0, p1);
      ld64<FAST>(&gates[(size_t)bg * 4672 + 2560 + nl + 2], p2, p3);
      float4 b4 = *(const float4*)&bD1[nl];
      float gi = g4.x + p0 + b4.x;
      float gf = g4.y + p1 + b4.y;
      float gz = g4.z + p2 + b4.z;
      float go = g4.w + p3 + b4.w;
      float cold = c1[(size_t)bg * 512 + ug];
      float cn = fsig(gf) * cold + fsig(gi) * ftanh(gz);
      float hn = fsig(go) * ftanh(cn);
      c1[(size_t)bg * 512 + ug] = cn;
      stha<FAST>(&hd1[(size_t)bg * 512 + ug], hn);
    }
    gbarf(g, r, ++bstep);
  }
}

// ---------------- kernel: detect XCD locality, dispatch mode ----------------
__global__ void __launch_bounds__(512, 2) kmain(const float* __restrict__ attn_v,
                                                const float* __restrict__ out_b,
                                                float* __restrict__ out) {
  __shared__ __align__(16) char asg[73728];   // 9 slots x 8 waves x 1KB
  __shared__ float red[16384];                // reduction buffers/zones (64KB)
  __shared__ int smode;

  const int g = blockIdx.x & 7;
  const int r = blockIdx.x >> 3;

  int xcc = 0;
  asm volatile("s_getreg_b32 %0, hwreg(HW_REG_XCC_ID)" : "=s"(xcc));
  if (threadIdx.x == 0)
    __hip_atomic_store(&g_xcc[blockIdx.x], xcc + 1,
                       __ATOMIC_RELAXED, __HIP_MEMORY_SCOPE_AGENT);
  gbar_acq8();
  if (threadIdx.x < 64) {
    // FAST requires: my group's 32 ids uniform AND != neighbor group's ids.
    // A constant-garbage getreg fails the diversity test -> SLOW (safe).
    int p = __hip_atomic_load(&g_xcc[((threadIdx.x & 31) << 3) | g],
                              __ATOMIC_RELAXED, __HIP_MEMORY_SCOPE_AGENT);
    int q = __hip_atomic_load(&g_xcc[((threadIdx.x & 31) << 3) | (g ^ 1)],
                              __ATOMIC_RELAXED, __HIP_MEMORY_SCOPE_AGENT);
    int p0 = __builtin_amdgcn_readfirstlane(p);
    int ok = (__all(p == p0) && !__all(q == p0)) ? 1 : 0;
    if (threadIdx.x == 0) smode = ok;
  }
  __syncthreads();
  if (smode) run_all<true>(g, r, attn_v, out_b, out, asg, red);
  else       run_all<false>(g, r, attn_v, out_b, out, asg, red);
}

// ---------------- prep kernels ----------------
__global__ void kpackB(size_t dstOff, int id, int Ntiles, int NC,
                       const float* s0, const float* s1,
                       const float* s2, const float* s3) {
  half_t* dst = (half_t*)(g_ws + dstOff);
  size_t total = (size_t)Ntiles * NC * 8192;
  size_t i = (size_t)blockIdx.x * 256 + threadIdx.x;
  size_t stride = (size_t)gridDim.x * 256;
  for (size_t e = i; e < total; e += stride) {
    int j = e & 7;
    int l = (e >> 3) & 63;
    int bh = (e >> 9) & 1;
    int w = (e >> 10) & 7;
    int tc = (int)(e >> 13);
    int c = tc % NC;
    int tile = tc / NC;
    int n = tile * 64 + bh * 32 + (l & 31);
    int k = c * 128 + w * 16 + ((l >> 5) << 3) + j;
    float v = 0.f;
    if (id == 0) {          // wL0: [Wih0(64) | pad(64) | Whh0(512)]
      int pn = gperm(n);
      if (k < 64) v = s0[(size_t)pn * 64 + k];
      else if (k >= 128) v = s1[(size_t)pn * 512 + (k - 128)];
    } else if (id == 1) {   // wL1: [Wih1(512) | Whh1(512)]
      int pn = gperm(n);
      v = (k < 512) ? s0[(size_t)pn * 512 + k] : s1[(size_t)pn * 512 + (k - 512)];
    } else if (id == 2) {   // wP1: [attnW | dWhh0 | dWhh1 | outW | pad]
      if (n < 512) v = s0[((size_t)n << 9) + k];
      else if (n < 2560) v = s1[((size_t)gperm(n - 512) << 9) + k];
      else if (n < 4608) v = s2[((size_t)gperm(n - 2560) << 9) + k];
      else if (n < 4611) v = s3[((size_t)(n - 4608) << 9) + k];
    } else if (id == 3) {   // wD0: dec_Wih0[:,1:]
      v = s0[(size_t)gperm(n) * 513 + 1 + k];
    } else {                // wD1
      v = s0[((size_t)gperm(n) << 9) + k];
    }
    dst[e] = (half_t)v;
  }
}

__global__ void kmisc(const float* ebih0, const float* ebhh0, const float* ebih1, const float* ebhh1,
                      const float* dbih0, const float* dbhh0, const float* dbih1, const float* dbhh1,
                      const float* dWih0, const float* x) {
  float* bL0 = WSF(O_BL0);
  float* bL1 = WSF(O_BL1);
  float* bD0 = WSF(O_BD0);
  float* bD1 = WSF(O_BD1);
  float* w0c = WSF(O_W0C);
  half_t* h0b = WSH(O_H0B);
  half_t* h1b = WSH(O_H1B);
  float* c1 = WSF(O_C1);
  float* inp = WSF(O_INP);
  int i = blockIdx.x * 256 + threadIdx.x, stride = gridDim.x * 256;
  for (int idx = i; idx < 262144; idx += stride) {
    if (idx < 2048) {
      int pn = gperm(idx);
      bL0[idx] = ebih0[pn] + ebhh0[pn];
      bL1[idx] = ebih1[pn] + ebhh1[pn];
      bD0[idx] = dbih0[pn] + dbhh0[pn];
      bD1[idx] = dbih1[pn] + dbhh1[pn];
      w0c[idx] = dWih0[(size_t)pn * 513];
      g_bar[idx] = 0;
    }
    if (idx < 1024) g_flags[idx] = 0;
    if (idx < 256) { inp[idx] = x[((size_t)idx * 512 + 511) * 64]; g_xcc[idx] = 0; }
    h0b[idx] = (half_t)0.f;
    h1b[idx] = (half_t)0.f;
    if (idx < 131072) c1[idx] = 0.f;
  }
}

__global__ void kx16(const float* x) {
  half_t* dst = WSH(O_X16);   // (t, b, 128) zero-padded cols 64..127
  size_t i = (size_t)blockIdx.x * 256 + threadIdx.x;
  size_t stride = (size_t)gridDim.x * 256;
  for (size_t e = i; e < (size_t)512 * 256 * 128; e += stride) {
    int t = (int)(e >> 15);
    int b = (int)((e >> 7) & 255);
    int ii = (int)(e & 127);
    dst[e] = (ii < 64) ? (half_t)x[((size_t)b * 512 + t) * 64 + ii] : (half_t)0.f;
  }
}

// ---------------- launch ----------------
extern "C" void kernel_launch(void* const* d_in, const int* in_sizes, int n_in,
                              void* d_out, int out_size, void* d_ws, size_t ws_size,
                              hipStream_t stream) {
  const float* x     = (const float*)d_in[0];
  const float* eWih0 = (const float*)d_in[1];
  const float* eWhh0 = (const float*)d_in[2];
  const float* ebih0 = (const float*)d_in[3];
  const float* ebhh0 = (const float*)d_in[4];
  const float* eWih1 = (const float*)d_in[5];
  const float* eWhh1 = (const float*)d_in[6];
  const float* ebih1 = (const float*)d_in[7];
  const float* ebhh1 = (const float*)d_in[8];
  const float* dWih0 = (const float*)d_in[9];
  const float* dWhh0 = (const float*)d_in[10];
  const float* dbih0 = (const float*)d_in[11];
  const float* dbhh0 = (const float*)d_in[12];
  const float* dWih1 = (const float*)d_in[13];
  const float* dWhh1 = (const float*)d_in[14];
  const float* dbih1 = (const float*)d_in[15];
  const float* dbhh1 = (const float*)d_in[16];
  const float* attnW = (const float*)d_in[17];
  const float* attnv = (const float*)d_in[18];
  const float* outW  = (const float*)d_in[19];
  const float* outb  = (const float*)d_in[20];
  (void)in_sizes; (void)n_in; (void)out_size; (void)d_ws; (void)ws_size;

  kpackB<<<1024, 256, 0, stream>>>(O_WL0, 0, 32, 5, eWih0, eWhh0, nullptr, nullptr);
  kpackB<<<1024, 256, 0, stream>>>(O_WL1, 1, 32, 8, eWih1, eWhh1, nullptr, nullptr);
  kpackB<<<1024, 256, 0, stream>>>(O_WP1, 2, 73, 4, attnW, dWhh0, dWhh1, outW);
  kpackB<<<1024, 256, 0, stream>>>(O_WD0, 3, 32, 4, dWih0, nullptr, nullptr, nullptr);
  kpackB<<<1024, 256, 0, stream>>>(O_WD1, 4, 32, 4, dWih1, nullptr, nullptr, nullptr);
  kmisc<<<1024, 256, 0, stream>>>(ebih0, ebhh0, ebih1, ebhh1,
                                  dbih0, dbhh0, dbih1, dbhh1, dWih0, x);
  kx16<<<2048, 256, 0, stream>>>(x);

  float* outp = (float*)d_out;
  void* args[] = {(void*)&attnv, (void*)&outb, (void*)&outp};
  hipError_t e = hipLaunchCooperativeKernel((void*)kmain, dim3(256), dim3(512),
                                            args, 0, stream);
  if (e != hipSuccess) {
    kmain<<<dim3(256), dim3(512), 0, stream>>>(attnv, outb, outp);
  }
}